// Round 2
// baseline (2472.195 us; speedup 1.0000x reference)
//
#include <hip/hip_runtime.h>
#include <hip/hip_bf16.h>
#include <cstddef>
#include <cstdint>

#define TT 35
#define NVOX 20000
#define NTR 700000
#define FIN 7
#define GXD 128
#define GYD 128
#define GZD 10
#define NPOS 163840
#define BNEPS 1e-5f

// stats layout (float offsets): per group {sum[C], sq[C], scale[C], shift[C]}
#define S_BN1 0
#define S_BN2 64
#define S_BN3 320
#define S_C1  832
#define S_C2  1088
#define S_C3  1344
#define STATS_FLOATS 2048

// byte offsets inside ws (total 84,058,112 B ~= 84 MB)
#define O_STATS 0ull
#define O_OWNER 8192ull          // 163840 * 4
#define O_H3MAX 663552ull        // 2,560,000 f32
#define O_H3MIN 10903552ull      // 2,560,000 f32
#define O_DENSE 21143552ull      // bf16 128*NPOS
#define O_Y1    63086592ull      // bf16 64*NPOS
#define O_Y2    O_DENSE          // bf16 64*NPOS (dense dead after conv1)
#define O_Y3    O_Y1             // f32 2*NPOS (y1 dead after conv2)
#define WS_BYTES 84058112ull

__device__ __forceinline__ float bf2f(__hip_bfloat16 x) { return __bfloat162float(x); }
__device__ __forceinline__ __hip_bfloat16 f2bf(float x) { return __float2bfloat16(x); }
__device__ __forceinline__ void storev(float* p, size_t i, float v) { p[i] = v; }
__device__ __forceinline__ void storev(__hip_bfloat16* p, size_t i, float v) { p[i] = f2bf(v); }

// ------------------- BN1 stats -------------------
__global__ __launch_bounds__(256) void k_stats1(
    const float* __restrict__ vf, float* __restrict__ stats,
    const float* __restrict__ w1, const float* __restrict__ b1)
{
    __shared__ float w1s[112], b1s[16];
    __shared__ float ssum[16], ssq[16];
    int tid = threadIdx.x;
    for (int i = tid; i < 112; i += 256) w1s[i] = w1[i];
    if (tid < 16) { b1s[tid] = b1[tid]; ssum[tid] = 0.f; ssq[tid] = 0.f; }
    __syncthreads();

    float lsum[16], lsq[16];
#pragma unroll
    for (int u = 0; u < 16; ++u) { lsum[u] = 0.f; lsq[u] = 0.f; }

    for (int r = blockIdx.x * 256 + tid; r < NTR; r += gridDim.x * 256) {
        float v[FIN];
#pragma unroll
        for (int f = 0; f < FIN; ++f) v[f] = vf[(size_t)r * FIN + f];
#pragma unroll
        for (int u = 0; u < 16; ++u) {
            float h = b1s[u];
#pragma unroll
            for (int f = 0; f < FIN; ++f) h += v[f] * w1s[f * 16 + u];
            lsum[u] += h; lsq[u] += h * h;
        }
    }
#pragma unroll
    for (int u = 0; u < 16; ++u) {
        float a = lsum[u], b = lsq[u];
        for (int off = 32; off > 0; off >>= 1) {
            a += __shfl_down(a, off);
            b += __shfl_down(b, off);
        }
        if ((tid & 63) == 0) { atomicAdd(&ssum[u], a); atomicAdd(&ssq[u], b); }
    }
    __syncthreads();
    if (tid < 16) {
        atomicAdd(&stats[S_BN1 + tid], ssum[tid]);
        atomicAdd(&stats[S_BN1 + 16 + tid], ssq[tid]);
    }
}

// ------------------- finalize BN params -------------------
__global__ void k_finalize(float* __restrict__ stats, int base, int C, float invM,
                           const float* __restrict__ g, const float* __restrict__ be)
{
    int i = threadIdx.x;
    if (i < C) {
        float mean = stats[base + i] * invM;
        float var  = stats[base + C + i] * invM - mean * mean;
        float sc = g[i] * rsqrtf(var + BNEPS);
        stats[base + 2 * C + i] = sc;
        stats[base + 3 * C + i] = be[i] - mean * sc;
    }
}

// stage-1 recompute (h1->bn1->relu, laf, mask, pwcf into LDS pc[TT*32])
__device__ __forceinline__ void stage1(
    int tid, int n, const float* __restrict__ vf,
    const float* w1s, const float* b1s, const float* sc1, const float* sh1,
    float* pwf, float* laf, float* mk, float* pc)
{
    {
        int u = tid & 15, tg = tid >> 4;
        for (int t = tg; t < TT; t += 16) {
            const float* vr = vf + (size_t)(n * TT + t) * FIN;
            float vv[FIN];
#pragma unroll
            for (int f = 0; f < FIN; ++f) vv[f] = vr[f];
            float h = b1s[u];
#pragma unroll
            for (int f = 0; f < FIN; ++f) h += vv[f] * w1s[f * 16 + u];
            pwf[t * 16 + u] = fmaxf(h * sc1[u] + sh1[u], 0.f);
            if (u == 0) {
                float mx = vv[0];
#pragma unroll
                for (int f = 1; f < FIN; ++f) mx = fmaxf(mx, vv[f]);
                mk[t] = (mx != 0.f) ? 1.f : 0.f;
            }
        }
    }
    __syncthreads();
    if (tid < 16) {   // laf = max over t, PRE-mask
        float m = pwf[tid];
        for (int t = 1; t < TT; ++t) m = fmaxf(m, pwf[t * 16 + tid]);
        laf[tid] = m;
    }
    __syncthreads();
    {
        int c = tid & 31, tg = tid >> 5;
        for (int t = tg; t < TT; t += 8)
            pc[t * 32 + c] = (c < 16 ? pwf[t * 16 + c] : laf[c - 16]) * mk[t];
    }
    __syncthreads();
}

// ------------------- BN2 stats (recomputes stage 1) -------------------
__global__ __launch_bounds__(256) void k_stats2(
    const float* __restrict__ vf, float* __restrict__ stats,
    const float* __restrict__ w1, const float* __restrict__ b1,
    const float* __restrict__ w2, const float* __restrict__ b2)
{
    __shared__ float w1s[112], b1s[16], sc1[16], sh1[16];
    __shared__ float w2s[2048], b2s[64];
    __shared__ float pwf[TT * 16], laf[16], pc[TT * 32], mk[TT];
    __shared__ float sred[256];
    int tid = threadIdx.x;
    for (int i = tid; i < 112; i += 256) w1s[i] = w1[i];
    for (int i = tid; i < 2048; i += 256) w2s[i] = w2[i];
    if (tid < 16) {
        b1s[tid] = b1[tid];
        sc1[tid] = stats[S_BN1 + 32 + tid];
        sh1[tid] = stats[S_BN1 + 48 + tid];
    }
    if (tid >= 64 && tid < 128) b2s[tid - 64] = b2[tid - 64];
    __syncthreads();

    int v = tid & 63;
    float lsum = 0.f, lsq = 0.f;
    for (int n = blockIdx.x; n < NVOX; n += gridDim.x) {
        stage1(tid, n, vf, w1s, b1s, sc1, sh1, pwf, laf, mk, pc);
        {
            int tg = tid >> 6;
            for (int t = tg; t < TT; t += 4) {
                float h = b2s[v];
#pragma unroll
                for (int c = 0; c < 32; ++c) h += pc[t * 32 + c] * w2s[c * 64 + v];
                lsum += h; lsq += h * h;
            }
        }
        __syncthreads();
    }
    sred[tid] = lsum; __syncthreads();
    if (tid < 64)
        atomicAdd(&stats[S_BN2 + tid],
                  sred[tid] + sred[tid + 64] + sred[tid + 128] + sred[tid + 192]);
    __syncthreads();
    sred[tid] = lsq; __syncthreads();
    if (tid < 64)
        atomicAdd(&stats[S_BN2 + 64 + tid],
                  sred[tid] + sred[tid + 64] + sred[tid + 128] + sred[tid + 192]);
}

// ------------------- full VFE2 + FCN: h3 max/min + BN3 stats -------------------
__global__ __launch_bounds__(256) void k_vfe3(
    const float* __restrict__ vf, float* __restrict__ stats,
    float* __restrict__ h3max, float* __restrict__ h3min,
    const float* __restrict__ w1, const float* __restrict__ b1,
    const float* __restrict__ w2, const float* __restrict__ b2,
    const float* __restrict__ w3, const float* __restrict__ b3)
{
    __shared__ float w1s[112], b1s[16], sc1[16], sh1[16];
    __shared__ float w2s[2048], b2s[64], sc2[64], sh2[64], b3s[128];
    __shared__ float pwf[TT * 16], laf[16], pc[TT * 32], mk[TT];
    __shared__ float pwf2[TT * 64], laf2[64], pc2[TT * 128];
    __shared__ float sred[256];
    int tid = threadIdx.x;
    for (int i = tid; i < 112; i += 256) w1s[i] = w1[i];
    for (int i = tid; i < 2048; i += 256) w2s[i] = w2[i];
    if (tid < 16) {
        b1s[tid] = b1[tid];
        sc1[tid] = stats[S_BN1 + 32 + tid];
        sh1[tid] = stats[S_BN1 + 48 + tid];
    }
    if (tid < 64) {
        b2s[tid] = b2[tid];
        sc2[tid] = stats[S_BN2 + 128 + tid];
        sh2[tid] = stats[S_BN2 + 192 + tid];
    }
    if (tid < 128) b3s[tid] = b3[tid];
    __syncthreads();

    int k4 = tid & 31, tg8 = tid >> 5;
    float ls[4] = {0.f, 0.f, 0.f, 0.f}, lq[4] = {0.f, 0.f, 0.f, 0.f};

    for (int n = blockIdx.x; n < NVOX; n += gridDim.x) {
        stage1(tid, n, vf, w1s, b1s, sc1, sh1, pwf, laf, mk, pc);
        { // h2 -> bn2 -> relu
            int v = tid & 63, tg = tid >> 6;
            for (int t = tg; t < TT; t += 4) {
                float h = b2s[v];
#pragma unroll
                for (int c = 0; c < 32; ++c) h += pc[t * 32 + c] * w2s[c * 64 + v];
                pwf2[t * 64 + v] = fmaxf(h * sc2[v] + sh2[v], 0.f);
            }
        }
        __syncthreads();
        if (tid < 64) {
            float m = pwf2[tid];
            for (int t = 1; t < TT; ++t) m = fmaxf(m, pwf2[t * 64 + tid]);
            laf2[tid] = m;
        }
        __syncthreads();
        {
            int c = tid & 127, tg = tid >> 7;
            for (int t = tg; t < TT; t += 2)
                pc2[t * 128 + c] = (c < 64 ? pwf2[t * 64 + c] : laf2[c - 64]) * mk[t];
        }
        __syncthreads();
        { // h3 = pc2 @ w3 + b3  (register tile 4k x 5t), reduce to max/min
            float acc[4][5];
#pragma unroll
            for (int j = 0; j < 4; ++j)
#pragma unroll
                for (int ti = 0; ti < 5; ++ti) acc[j][ti] = b3s[k4 + 32 * j];
            for (int c = 0; c < 128; ++c) {
                float wv[4];
#pragma unroll
                for (int j = 0; j < 4; ++j) wv[j] = w3[c * 128 + k4 + 32 * j];
                float p[5];
#pragma unroll
                for (int ti = 0; ti < 5; ++ti) {
                    int t = tg8 + 8 * ti;
                    p[ti] = (t < TT) ? pc2[t * 128 + c] : 0.f;
                }
#pragma unroll
                for (int j = 0; j < 4; ++j)
#pragma unroll
                    for (int ti = 0; ti < 5; ++ti) acc[j][ti] += p[ti] * wv[j];
            }
            float lmax[4], lmin[4];
#pragma unroll
            for (int j = 0; j < 4; ++j) { lmax[j] = -1e30f; lmin[j] = 1e30f; }
#pragma unroll
            for (int ti = 0; ti < 5; ++ti) {
                int t = tg8 + 8 * ti;
                if (t < TT) {
#pragma unroll
                    for (int j = 0; j < 4; ++j) {
                        float h = acc[j][ti];
                        ls[j] += h; lq[j] += h * h;
                        lmax[j] = fmaxf(lmax[j], h);
                        lmin[j] = fminf(lmin[j], h);
                    }
                }
            }
#pragma unroll
            for (int j = 0; j < 4; ++j) {
                sred[tid] = lmax[j]; __syncthreads();
                if (tid < 32) {
                    float m = sred[tid];
                    for (int g = 1; g < 8; ++g) m = fmaxf(m, sred[tid + 32 * g]);
                    h3max[(size_t)n * 128 + tid + 32 * j] = m;
                }
                __syncthreads();
                sred[tid] = lmin[j]; __syncthreads();
                if (tid < 32) {
                    float m = sred[tid];
                    for (int g = 1; g < 8; ++g) m = fminf(m, sred[tid + 32 * g]);
                    h3min[(size_t)n * 128 + tid + 32 * j] = m;
                }
                __syncthreads();
            }
        }
    }
#pragma unroll
    for (int j = 0; j < 4; ++j) {
        sred[tid] = ls[j]; __syncthreads();
        if (tid < 32) {
            float a = 0.f;
            for (int m = 0; m < 8; ++m) a += sred[tid + 32 * m];
            atomicAdd(&stats[S_BN3 + k4 + 32 * j], a);
        }
        __syncthreads();
        sred[tid] = lq[j]; __syncthreads();
        if (tid < 32) {
            float a = 0.f;
            for (int m = 0; m < 8; ++m) a += sred[tid + 32 * m];
            atomicAdd(&stats[S_BN3 + 128 + k4 + 32 * j], a);
        }
        __syncthreads();
    }
}

// ------------------- owner resolution (last index wins) -------------------
__global__ void k_owner(const int* __restrict__ coords, int* __restrict__ owner)
{
    int n = blockIdx.x * 256 + threadIdx.x;
    if (n >= NVOX) return;
    int cx = coords[n * 4 + 1], cy = coords[n * 4 + 2], cz = coords[n * 4 + 3];
    atomicMax(&owner[(cx * GYD + cy) * GZD + cz], n);
}

// ------------------- bn3+relu via max/min, scatter into dense (bf16) ----------
__global__ __launch_bounds__(128) void k_scatter(
    const float* __restrict__ h3max, const float* __restrict__ h3min,
    const int* __restrict__ coords, const int* __restrict__ owner,
    const float* __restrict__ stats, __hip_bfloat16* __restrict__ dense)
{
    int n = blockIdx.x, k = threadIdx.x;
    int cx = coords[n * 4 + 1], cy = coords[n * 4 + 2], cz = coords[n * 4 + 3];
    int cell = (cx * GYD + cy) * GZD + cz;
    if (owner[cell] != n) return;
    float sc = stats[S_BN3 + 256 + k], sh = stats[S_BN3 + 384 + k];
    // relu(affine) is monotone: max_t relu(sc*h+sh) = relu(sc*(sc>=0?hmax:hmin)+sh)
    float h = (sc >= 0.f) ? h3max[(size_t)n * 128 + k] : h3min[(size_t)n * 128 + k];
    dense[(size_t)k * NPOS + cell] = f2bf(fmaxf(h * sc + sh, 0.f));
}

// ------------------- direct 3x3x3 conv + bias + BN stats -------------------
template <int IC, int OCB, typename OT>
__global__ __launch_bounds__(256) void k_conv(
    const __hip_bfloat16* __restrict__ in, const float* __restrict__ w,
    const float* __restrict__ bias, OT* __restrict__ outp,
    float* __restrict__ sumAcc, float* __restrict__ sqAcc)
{
    int tid = threadIdx.x;
    int col = blockIdx.x * 256 + tid;     // (x,y)
    int x = col >> 7, y = col & 127;
    int ocb = blockIdx.y * OCB;

    float acc[GZD][OCB];
#pragma unroll
    for (int z = 0; z < GZD; ++z)
#pragma unroll
        for (int o = 0; o < OCB; ++o) acc[z][o] = 0.f;

    for (int dxy = 0; dxy < 9; ++dxy) {
        int dx = dxy / 3 - 1, dy = dxy % 3 - 1;
        int xs = x + dx, ys = y + dy;
        if (xs < 0 || xs >= GXD || ys < 0 || ys >= GYD) continue;
        const __hip_bfloat16* ip = in + (size_t)(xs * GYD + ys) * GZD;
        const float* wp = w + (size_t)ocb * IC * 27 + dxy * 3;
        for (int ic = 0; ic < IC; ++ic) {
            float c[GZD];
#pragma unroll
            for (int z = 0; z < GZD; ++z) c[z] = bf2f(ip[(size_t)ic * NPOS + z]);
            float wg[OCB][3];
#pragma unroll
            for (int o = 0; o < OCB; ++o)
#pragma unroll
                for (int dz = 0; dz < 3; ++dz)
                    wg[o][dz] = wp[(size_t)(o * IC + ic) * 27 + dz];
#pragma unroll
            for (int z = 0; z < GZD; ++z)
#pragma unroll
                for (int dz = 0; dz < 3; ++dz) {
                    int zz = z + dz - 1;
                    if (zz < 0 || zz >= GZD) continue;
#pragma unroll
                    for (int o = 0; o < OCB; ++o) acc[z][o] += c[zz] * wg[o][dz];
                }
        }
    }

    float ls[OCB], lq[OCB];
#pragma unroll
    for (int o = 0; o < OCB; ++o) { ls[o] = 0.f; lq[o] = 0.f; }
#pragma unroll
    for (int o = 0; o < OCB; ++o) {
        float bb = bias[ocb + o];
        for (int z = 0; z < GZD; ++z) {
            float t = acc[z][o] + bb;
            storev(outp, (size_t)(ocb + o) * NPOS + col * GZD + z, t);
            ls[o] += t; lq[o] += t * t;
        }
    }
    __shared__ float sred[256];
    for (int o = 0; o < OCB; ++o) {
        sred[tid] = ls[o]; __syncthreads();
        for (int s = 128; s > 0; s >>= 1) {
            if (tid < s) sred[tid] += sred[tid + s];
            __syncthreads();
        }
        if (tid == 0) atomicAdd(&sumAcc[ocb + o], sred[0]);
        __syncthreads();
        sred[tid] = lq[o]; __syncthreads();
        for (int s = 128; s > 0; s >>= 1) {
            if (tid < s) sred[tid] += sred[tid + s];
            __syncthreads();
        }
        if (tid == 0) atomicAdd(&sqAcc[ocb + o], sred[0]);
        __syncthreads();
    }
}

// ------------------- elementwise bn + relu (bf16 in place) -------------------
__global__ void k_bnrelu_bf(__hip_bfloat16* __restrict__ y,
                            const float* __restrict__ stats, int base, int C)
{
    int total = C * NPOS;
    for (int i = blockIdx.x * 256 + threadIdx.x; i < total; i += gridDim.x * 256) {
        int c = i / NPOS;
        y[i] = f2bf(fmaxf(bf2f(y[i]) * stats[base + 2 * C + c] + stats[base + 3 * C + c], 0.f));
    }
}

// ------------------- gather + bn + relu + softmax -------------------
__global__ void k_out(const float* __restrict__ y3, const int* __restrict__ coords,
                      const float* __restrict__ stats, float* __restrict__ out)
{
    int n = blockIdx.x * 256 + threadIdx.x;
    if (n >= NVOX) return;
    int cx = coords[n * 4 + 1], cy = coords[n * 4 + 2], cz = coords[n * 4 + 3];
    int cell = (cx * GYD + cy) * GZD + cz;
    float a = fmaxf(y3[cell] * stats[S_C3 + 4] + stats[S_C3 + 6], 0.f);
    float b = fmaxf(y3[(size_t)NPOS + cell] * stats[S_C3 + 5] + stats[S_C3 + 7], 0.f);
    float m = fmaxf(a, b);
    float e0 = expf(a - m), e1 = expf(b - m);
    float inv = 1.f / (e0 + e1);
    out[n * 2 + 0] = e0 * inv;
    out[n * 2 + 1] = e1 * inv;
}

extern "C" void kernel_launch(void* const* d_in, const int* in_sizes, int n_in,
                              void* d_out, int out_size, void* d_ws, size_t ws_size,
                              hipStream_t stream)
{
    const float* vf     = (const float*)d_in[0];
    const int*   coords = (const int*)d_in[1];
    const float* w1  = (const float*)d_in[2];
    const float* b1  = (const float*)d_in[3];
    const float* g1  = (const float*)d_in[4];
    const float* be1 = (const float*)d_in[5];
    const float* w2  = (const float*)d_in[6];
    const float* b2  = (const float*)d_in[7];
    const float* g2  = (const float*)d_in[8];
    const float* be2 = (const float*)d_in[9];
    const float* w3  = (const float*)d_in[10];
    const float* b3  = (const float*)d_in[11];
    const float* g3  = (const float*)d_in[12];
    const float* be3 = (const float*)d_in[13];
    const float* c1w = (const float*)d_in[14];
    const float* c1b = (const float*)d_in[15];
    const float* c1g = (const float*)d_in[16];
    const float* c1be= (const float*)d_in[17];
    const float* c2w = (const float*)d_in[18];
    const float* c2b = (const float*)d_in[19];
    const float* c2g = (const float*)d_in[20];
    const float* c2be= (const float*)d_in[21];
    const float* c3w = (const float*)d_in[22];
    const float* c3b = (const float*)d_in[23];
    const float* c3g = (const float*)d_in[24];
    const float* c3be= (const float*)d_in[25];

    if (ws_size < WS_BYTES) return;

    char* base = (char*)d_ws;
    float* stats = (float*)(base + O_STATS);
    int*   owner = (int*)(base + O_OWNER);
    float* h3max = (float*)(base + O_H3MAX);
    float* h3min = (float*)(base + O_H3MIN);
    __hip_bfloat16* dense = (__hip_bfloat16*)(base + O_DENSE);
    __hip_bfloat16* y1    = (__hip_bfloat16*)(base + O_Y1);
    __hip_bfloat16* y2    = (__hip_bfloat16*)(base + O_Y2);
    float* y3             = (float*)(base + O_Y3);

    hipMemsetAsync(stats, 0, STATS_FLOATS * sizeof(float), stream);
    hipMemsetAsync(owner, 0xFF, (size_t)NPOS * sizeof(int), stream);
    hipMemsetAsync((void*)dense, 0, (size_t)128 * NPOS * sizeof(__hip_bfloat16), stream);

    k_stats1<<<1024, 256, 0, stream>>>(vf, stats, w1, b1);
    k_finalize<<<1, 128, 0, stream>>>(stats, S_BN1, 16, 1.f / NTR, g1, be1);
    k_stats2<<<2048, 256, 0, stream>>>(vf, stats, w1, b1, w2, b2);
    k_finalize<<<1, 128, 0, stream>>>(stats, S_BN2, 64, 1.f / NTR, g2, be2);
    k_vfe3<<<2048, 256, 0, stream>>>(vf, stats, h3max, h3min, w1, b1, w2, b2, w3, b3);
    k_finalize<<<1, 128, 0, stream>>>(stats, S_BN3, 128, 1.f / NTR, g3, be3);
    k_owner<<<(NVOX + 255) / 256, 256, 0, stream>>>(coords, owner);
    k_scatter<<<NVOX, 128, 0, stream>>>(h3max, h3min, coords, owner, stats, dense);

    k_conv<128, 4, __hip_bfloat16><<<dim3(64, 16), 256, 0, stream>>>(
        dense, c1w, c1b, y1, &stats[S_C1], &stats[S_C1 + 64]);
    k_finalize<<<1, 128, 0, stream>>>(stats, S_C1, 64, 1.f / NPOS, c1g, c1be);
    k_bnrelu_bf<<<2048, 256, 0, stream>>>(y1, stats, S_C1, 64);

    k_conv<64, 4, __hip_bfloat16><<<dim3(64, 16), 256, 0, stream>>>(
        y1, c2w, c2b, y2, &stats[S_C2], &stats[S_C2 + 64]);
    k_finalize<<<1, 128, 0, stream>>>(stats, S_C2, 64, 1.f / NPOS, c2g, c2be);
    k_bnrelu_bf<<<2048, 256, 0, stream>>>(y2, stats, S_C2, 64);

    k_conv<64, 2, float><<<dim3(64, 1), 256, 0, stream>>>(
        y2, c3w, c3b, y3, &stats[S_C3], &stats[S_C3 + 2]);
    k_finalize<<<1, 128, 0, stream>>>(stats, S_C3, 2, 1.f / NPOS, c3g, c3be);

    k_out<<<(NVOX + 255) / 256, 256, 0, stream>>>(y3, coords, stats, (float*)d_out);
}

// Round 3
// 1713.267 us; speedup vs baseline: 1.4430x; 1.4430x over previous
//
#include <hip/hip_runtime.h>
#include <hip/hip_bf16.h>
#include <cstddef>
#include <cstdint>

#define TT 35
#define NVOX 20000
#define NTR 700000
#define FIN 7
#define GXD 128
#define GYD 128
#define GZD 10
#define NPOS 163840
#define BNEPS 1e-5f

// stats layout (float offsets): per group {sum[C], sq[C], scale[C], shift[C]}
#define S_BN1 0
#define S_BN2 64
#define S_BN3 320
#define S_C1  832
#define S_C2  1088
#define S_C3  1344
#define STATS_FLOATS 2048

// byte offsets inside ws
#define O_STATS 0ull
#define O_ZERO  8192ull           // 256 B zero page
#define O_OWNER 12288ull          // 163840*4
#define O_H3MAX 667648ull         // 20000*128*4
#define O_H3MIN 10907648ull       // 20000*128*4
#define O_WB1   667648ull         // bf16 27*64*128 (overlays h3max, used after scatter)
#define O_WB2   1110016ull        // bf16 27*64*64
#define O_DENSE 21147648ull       // bf16 [NPOS][128]
#define O_Y1    63090688ull       // bf16 [NPOS][64]
#define O_Y2    O_DENSE           // bf16 [NPOS][64] (dense dead after conv1)
#define O_Y3    O_H3MIN           // f32 [NPOS][2]  (h3min dead after scatter)
#define WS_BYTES 84062208ull

typedef __attribute__((ext_vector_type(8))) short short8;
typedef __attribute__((ext_vector_type(4))) float f32x4;

__device__ __forceinline__ float bf2f(__hip_bfloat16 x) { return __bfloat162float(x); }
__device__ __forceinline__ __hip_bfloat16 f2bf(float x) { return __float2bfloat16(x); }
__device__ __forceinline__ float bfs2f(short s) {
    union { unsigned u; float f; } cv; cv.u = ((unsigned)(unsigned short)s) << 16; return cv.f;
}
__device__ __forceinline__ short f2bfs(float f) {
    __hip_bfloat16 h = __float2bfloat16(f);
    return *(short*)&h;
}

// ------------------- BN1 stats -------------------
__global__ __launch_bounds__(256) void k_stats1(
    const float* __restrict__ vf, float* __restrict__ stats,
    const float* __restrict__ w1, const float* __restrict__ b1)
{
    __shared__ float w1s[112], b1s[16];
    __shared__ float ssum[16], ssq[16];
    int tid = threadIdx.x;
    for (int i = tid; i < 112; i += 256) w1s[i] = w1[i];
    if (tid < 16) { b1s[tid] = b1[tid]; ssum[tid] = 0.f; ssq[tid] = 0.f; }
    __syncthreads();

    float lsum[16], lsq[16];
#pragma unroll
    for (int u = 0; u < 16; ++u) { lsum[u] = 0.f; lsq[u] = 0.f; }

    for (int r = blockIdx.x * 256 + tid; r < NTR; r += gridDim.x * 256) {
        float v[FIN];
#pragma unroll
        for (int f = 0; f < FIN; ++f) v[f] = vf[(size_t)r * FIN + f];
#pragma unroll
        for (int u = 0; u < 16; ++u) {
            float h = b1s[u];
#pragma unroll
            for (int f = 0; f < FIN; ++f) h += v[f] * w1s[f * 16 + u];
            lsum[u] += h; lsq[u] += h * h;
        }
    }
#pragma unroll
    for (int u = 0; u < 16; ++u) {
        float a = lsum[u], b = lsq[u];
        for (int off = 32; off > 0; off >>= 1) {
            a += __shfl_down(a, off);
            b += __shfl_down(b, off);
        }
        if ((tid & 63) == 0) { atomicAdd(&ssum[u], a); atomicAdd(&ssq[u], b); }
    }
    __syncthreads();
    if (tid < 16) {
        atomicAdd(&stats[S_BN1 + tid], ssum[tid]);
        atomicAdd(&stats[S_BN1 + 16 + tid], ssq[tid]);
    }
}

// ------------------- finalize BN params -------------------
__global__ void k_finalize(float* __restrict__ stats, int base, int C, float invM,
                           const float* __restrict__ g, const float* __restrict__ be)
{
    int i = threadIdx.x;
    if (i < C) {
        float mean = stats[base + i] * invM;
        float var  = stats[base + C + i] * invM - mean * mean;
        float sc = g[i] * rsqrtf(var + BNEPS);
        stats[base + 2 * C + i] = sc;
        stats[base + 3 * C + i] = be[i] - mean * sc;
    }
}

// stage-1 recompute (h1->bn1->relu, laf, mask, pwcf into LDS pc[TT*32])
__device__ __forceinline__ void stage1(
    int tid, int n, const float* __restrict__ vf,
    const float* w1s, const float* b1s, const float* sc1, const float* sh1,
    float* pwf, float* laf, float* mk, float* pc)
{
    {
        int u = tid & 15, tg = tid >> 4;
        for (int t = tg; t < TT; t += 16) {
            const float* vr = vf + (size_t)(n * TT + t) * FIN;
            float vv[FIN];
#pragma unroll
            for (int f = 0; f < FIN; ++f) vv[f] = vr[f];
            float h = b1s[u];
#pragma unroll
            for (int f = 0; f < FIN; ++f) h += vv[f] * w1s[f * 16 + u];
            pwf[t * 16 + u] = fmaxf(h * sc1[u] + sh1[u], 0.f);
            if (u == 0) {
                float mx = vv[0];
#pragma unroll
                for (int f = 1; f < FIN; ++f) mx = fmaxf(mx, vv[f]);
                mk[t] = (mx != 0.f) ? 1.f : 0.f;
            }
        }
    }
    __syncthreads();
    if (tid < 16) {   // laf = max over t, PRE-mask
        float m = pwf[tid];
        for (int t = 1; t < TT; ++t) m = fmaxf(m, pwf[t * 16 + tid]);
        laf[tid] = m;
    }
    __syncthreads();
    {
        int c = tid & 31, tg = tid >> 5;
        for (int t = tg; t < TT; t += 8)
            pc[t * 32 + c] = (c < 16 ? pwf[t * 16 + c] : laf[c - 16]) * mk[t];
    }
    __syncthreads();
}

// ------------------- BN2 stats (recomputes stage 1) -------------------
__global__ __launch_bounds__(256) void k_stats2(
    const float* __restrict__ vf, float* __restrict__ stats,
    const float* __restrict__ w1, const float* __restrict__ b1,
    const float* __restrict__ w2, const float* __restrict__ b2)
{
    __shared__ float w1s[112], b1s[16], sc1[16], sh1[16];
    __shared__ float w2s[2048], b2s[64];
    __shared__ float pwf[TT * 16], laf[16], pc[TT * 32], mk[TT];
    __shared__ float sred[256];
    int tid = threadIdx.x;
    for (int i = tid; i < 112; i += 256) w1s[i] = w1[i];
    for (int i = tid; i < 2048; i += 256) w2s[i] = w2[i];
    if (tid < 16) {
        b1s[tid] = b1[tid];
        sc1[tid] = stats[S_BN1 + 32 + tid];
        sh1[tid] = stats[S_BN1 + 48 + tid];
    }
    if (tid >= 64 && tid < 128) b2s[tid - 64] = b2[tid - 64];
    __syncthreads();

    int v = tid & 63;
    float lsum = 0.f, lsq = 0.f;
    for (int n = blockIdx.x; n < NVOX; n += gridDim.x) {
        stage1(tid, n, vf, w1s, b1s, sc1, sh1, pwf, laf, mk, pc);
        {
            int tg = tid >> 6;
            for (int t = tg; t < TT; t += 4) {
                float h = b2s[v];
#pragma unroll
                for (int c = 0; c < 32; ++c) h += pc[t * 32 + c] * w2s[c * 64 + v];
                lsum += h; lsq += h * h;
            }
        }
        __syncthreads();
    }
    sred[tid] = lsum; __syncthreads();
    if (tid < 64)
        atomicAdd(&stats[S_BN2 + tid],
                  sred[tid] + sred[tid + 64] + sred[tid + 128] + sred[tid + 192]);
    __syncthreads();
    sred[tid] = lsq; __syncthreads();
    if (tid < 64)
        atomicAdd(&stats[S_BN2 + 64 + tid],
                  sred[tid] + sred[tid + 64] + sred[tid + 128] + sred[tid + 192]);
}

// ------------------- full VFE2 + FCN: h3 max/min + BN3 stats -------------------
__global__ __launch_bounds__(256) void k_vfe3(
    const float* __restrict__ vf, float* __restrict__ stats,
    float* __restrict__ h3max, float* __restrict__ h3min,
    const float* __restrict__ w1, const float* __restrict__ b1,
    const float* __restrict__ w2, const float* __restrict__ b2,
    const float* __restrict__ w3, const float* __restrict__ b3)
{
    __shared__ float w1s[112], b1s[16], sc1[16], sh1[16];
    __shared__ float w2s[2048], b2s[64], sc2[64], sh2[64], b3s[128];
    __shared__ float pwf[TT * 16], laf[16], pc[TT * 32], mk[TT];
    __shared__ float pwf2[TT * 64], laf2[64], pc2[TT * 128];
    __shared__ float sred[256];
    int tid = threadIdx.x;
    for (int i = tid; i < 112; i += 256) w1s[i] = w1[i];
    for (int i = tid; i < 2048; i += 256) w2s[i] = w2[i];
    if (tid < 16) {
        b1s[tid] = b1[tid];
        sc1[tid] = stats[S_BN1 + 32 + tid];
        sh1[tid] = stats[S_BN1 + 48 + tid];
    }
    if (tid < 64) {
        b2s[tid] = b2[tid];
        sc2[tid] = stats[S_BN2 + 128 + tid];
        sh2[tid] = stats[S_BN2 + 192 + tid];
    }
    if (tid < 128) b3s[tid] = b3[tid];
    __syncthreads();

    int k4 = tid & 31, tg8 = tid >> 5;
    float ls[4] = {0.f, 0.f, 0.f, 0.f}, lq[4] = {0.f, 0.f, 0.f, 0.f};

    for (int n = blockIdx.x; n < NVOX; n += gridDim.x) {
        stage1(tid, n, vf, w1s, b1s, sc1, sh1, pwf, laf, mk, pc);
        { // h2 -> bn2 -> relu
            int v = tid & 63, tg = tid >> 6;
            for (int t = tg; t < TT; t += 4) {
                float h = b2s[v];
#pragma unroll
                for (int c = 0; c < 32; ++c) h += pc[t * 32 + c] * w2s[c * 64 + v];
                pwf2[t * 64 + v] = fmaxf(h * sc2[v] + sh2[v], 0.f);
            }
        }
        __syncthreads();
        if (tid < 64) {
            float m = pwf2[tid];
            for (int t = 1; t < TT; ++t) m = fmaxf(m, pwf2[t * 64 + tid]);
            laf2[tid] = m;
        }
        __syncthreads();
        {
            int c = tid & 127, tg = tid >> 7;
            for (int t = tg; t < TT; t += 2)
                pc2[t * 128 + c] = (c < 64 ? pwf2[t * 64 + c] : laf2[c - 64]) * mk[t];
        }
        __syncthreads();
        { // h3 = pc2 @ w3 + b3  (register tile 4k x 5t), reduce to max/min
            float acc[4][5];
#pragma unroll
            for (int j = 0; j < 4; ++j)
#pragma unroll
                for (int ti = 0; ti < 5; ++ti) acc[j][ti] = b3s[k4 + 32 * j];
            for (int c = 0; c < 128; ++c) {
                float wv[4];
#pragma unroll
                for (int j = 0; j < 4; ++j) wv[j] = w3[c * 128 + k4 + 32 * j];
                float p[5];
#pragma unroll
                for (int ti = 0; ti < 5; ++ti) {
                    int t = tg8 + 8 * ti;
                    p[ti] = (t < TT) ? pc2[t * 128 + c] : 0.f;
                }
#pragma unroll
                for (int j = 0; j < 4; ++j)
#pragma unroll
                    for (int ti = 0; ti < 5; ++ti) acc[j][ti] += p[ti] * wv[j];
            }
            float lmax[4], lmin[4];
#pragma unroll
            for (int j = 0; j < 4; ++j) { lmax[j] = -1e30f; lmin[j] = 1e30f; }
#pragma unroll
            for (int ti = 0; ti < 5; ++ti) {
                int t = tg8 + 8 * ti;
                if (t < TT) {
#pragma unroll
                    for (int j = 0; j < 4; ++j) {
                        float h = acc[j][ti];
                        ls[j] += h; lq[j] += h * h;
                        lmax[j] = fmaxf(lmax[j], h);
                        lmin[j] = fminf(lmin[j], h);
                    }
                }
            }
#pragma unroll
            for (int j = 0; j < 4; ++j) {
                sred[tid] = lmax[j]; __syncthreads();
                if (tid < 32) {
                    float m = sred[tid];
                    for (int g = 1; g < 8; ++g) m = fmaxf(m, sred[tid + 32 * g]);
                    h3max[(size_t)n * 128 + tid + 32 * j] = m;
                }
                __syncthreads();
                sred[tid] = lmin[j]; __syncthreads();
                if (tid < 32) {
                    float m = sred[tid];
                    for (int g = 1; g < 8; ++g) m = fminf(m, sred[tid + 32 * g]);
                    h3min[(size_t)n * 128 + tid + 32 * j] = m;
                }
                __syncthreads();
            }
        }
    }
#pragma unroll
    for (int j = 0; j < 4; ++j) {
        sred[tid] = ls[j]; __syncthreads();
        if (tid < 32) {
            float a = 0.f;
            for (int m = 0; m < 8; ++m) a += sred[tid + 32 * m];
            atomicAdd(&stats[S_BN3 + k4 + 32 * j], a);
        }
        __syncthreads();
        sred[tid] = lq[j]; __syncthreads();
        if (tid < 32) {
            float a = 0.f;
            for (int m = 0; m < 8; ++m) a += sred[tid + 32 * m];
            atomicAdd(&stats[S_BN3 + 128 + k4 + 32 * j], a);
        }
        __syncthreads();
    }
}

// ------------------- owner resolution (last index wins) -------------------
__global__ void k_owner(const int* __restrict__ coords, int* __restrict__ owner)
{
    int n = blockIdx.x * 256 + threadIdx.x;
    if (n >= NVOX) return;
    int cx = coords[n * 4 + 1], cy = coords[n * 4 + 2], cz = coords[n * 4 + 3];
    atomicMax(&owner[(cx * GYD + cy) * GZD + cz], n);
}

// ---------- bn3+relu via max/min, scatter into dense [NPOS][128] bf16 ----------
__global__ __launch_bounds__(128) void k_scatter(
    const float* __restrict__ h3max, const float* __restrict__ h3min,
    const int* __restrict__ coords, const int* __restrict__ owner,
    const float* __restrict__ stats, __hip_bfloat16* __restrict__ dense)
{
    int n = blockIdx.x, k = threadIdx.x;
    int cx = coords[n * 4 + 1], cy = coords[n * 4 + 2], cz = coords[n * 4 + 3];
    int cell = (cx * GYD + cy) * GZD + cz;
    if (owner[cell] != n) return;
    float sc = stats[S_BN3 + 256 + k], sh = stats[S_BN3 + 384 + k];
    float h = (sc >= 0.f) ? h3max[(size_t)n * 128 + k] : h3min[(size_t)n * 128 + k];
    dense[(size_t)cell * 128 + k] = f2bf(fmaxf(h * sc + sh, 0.f));
}

// ---------- weight relayout: src [OC][IC][27] f32 -> dst [27][OC][IC] bf16 ----------
__global__ void k_wcvt(const float* __restrict__ src, __hip_bfloat16* __restrict__ dst,
                       int OC, int IC)
{
    int i = blockIdx.x * 256 + threadIdx.x;
    int total = OC * IC * 27;
    if (i >= total) return;
    int d = i / (OC * IC);
    int rem = i - d * (OC * IC);
    int o = rem / IC, ic = rem - o * IC;
    dst[i] = f2bf(src[(o * IC + ic) * 27 + d]);
}

// ---------- MFMA implicit-GEMM 3x3x3 conv: in [NPOS][IC] -> out [NPOS][64] ----------
// WG = 256 thr = 4 waves; tile 64 pos x 64 oc; wave = 32 pos x 32 oc (2x2 mfma tiles).
template <int IC>
__global__ __launch_bounds__(256) void k_convm(
    const __hip_bfloat16* __restrict__ in, const __hip_bfloat16* __restrict__ wb,
    const float* __restrict__ bias, __hip_bfloat16* __restrict__ outp,
    const __hip_bfloat16* __restrict__ zp,
    float* __restrict__ sumAcc, float* __restrict__ sqAcc)
{
    constexpr int KS = IC / 32;              // ksteps per tap
    __shared__ float ssum[64], ssq[64];
    int tid = threadIdx.x;
    if (tid < 64) { ssum[tid] = 0.f; ssq[tid] = 0.f; }
    __syncthreads();

    int l = tid & 63, wave = tid >> 6;
    int wm = wave >> 1, wn = wave & 1;
    int lr = l & 15, lk = l >> 4;

    int pbase = blockIdx.x * 64;
    int p0 = pbase + wm * 32 + lr;           // A row for m-tile 0
    int p1 = p0 + 16;                        // m-tile 1
    int z0 = p0 % 10, y0 = (p0 / 10) % 128, x0 = p0 / 1280;
    int z1 = p1 % 10, y1c = (p1 / 10) % 128, x1 = p1 / 1280;

    int oc0 = wn * 32 + lr;                  // B col for n-tile 0
    int oc1 = oc0 + 16;
    const short8* wrow0 = (const short8*)(wb + (size_t)oc0 * IC + lk * 8);
    const short8* wrow1 = (const short8*)(wb + (size_t)oc1 * IC + lk * 8);
    const int tapstride = 64 * IC / 8;       // short8 units per tap

    float bb0 = bias[oc0], bb1 = bias[oc1];
    f32x4 acc[2][2];
#pragma unroll
    for (int t = 0; t < 2; ++t) {
        acc[t][0] = {bb0, bb0, bb0, bb0};
        acc[t][1] = {bb1, bb1, bb1, bb1};
    }

    for (int d = 0; d < 27; ++d) {
        int dx = d / 9 - 1, dy = (d / 3) % 3 - 1, dz = d % 3 - 1;
        int off = (dx * 128 + dy) * 10 + dz;
        bool v0 = ((unsigned)(x0 + dx) < 128u) & ((unsigned)(y0 + dy) < 128u) & ((unsigned)(z0 + dz) < 10u);
        bool v1 = ((unsigned)(x1 + dx) < 128u) & ((unsigned)(y1c + dy) < 128u) & ((unsigned)(z1 + dz) < 10u);
        const short8* a0p = v0 ? (const short8*)(in + (size_t)(p0 + off) * IC + lk * 8)
                               : (const short8*)zp;
        const short8* a1p = v1 ? (const short8*)(in + (size_t)(p1 + off) * IC + lk * 8)
                               : (const short8*)zp;
        const short8* b0p = wrow0 + (size_t)d * tapstride;
        const short8* b1p = wrow1 + (size_t)d * tapstride;
#pragma unroll
        for (int k = 0; k < KS; ++k) {
            short8 a0 = a0p[k * 4];
            short8 a1 = a1p[k * 4];
            short8 b0 = b0p[k * 4];
            short8 b1 = b1p[k * 4];
            acc[0][0] = __builtin_amdgcn_mfma_f32_16x16x32_bf16(a0, b0, acc[0][0], 0, 0, 0);
            acc[0][1] = __builtin_amdgcn_mfma_f32_16x16x32_bf16(a0, b1, acc[0][1], 0, 0, 0);
            acc[1][0] = __builtin_amdgcn_mfma_f32_16x16x32_bf16(a1, b0, acc[1][0], 0, 0, 0);
            acc[1][1] = __builtin_amdgcn_mfma_f32_16x16x32_bf16(a1, b1, acc[1][1], 0, 0, 0);
        }
    }

    // store: D row (position) = (lane>>4)*4 + reg, D col (oc) = lane&15
    float s0 = 0.f, q0 = 0.f, s1 = 0.f, q1 = 0.f;
#pragma unroll
    for (int t = 0; t < 2; ++t) {
#pragma unroll
        for (int r = 0; r < 4; ++r) {
            int prow = pbase + wm * 32 + t * 16 + lk * 4 + r;
            float v0c = acc[t][0][r], v1c = acc[t][1][r];
            outp[(size_t)prow * 64 + oc0] = f2bf(v0c);
            outp[(size_t)prow * 64 + oc1] = f2bf(v1c);
            s0 += v0c; q0 += v0c * v0c;
            s1 += v1c; q1 += v1c * v1c;
        }
    }
    // reduce across the 4 lk-groups sharing the same oc column
    s0 += __shfl_xor(s0, 16); s0 += __shfl_xor(s0, 32);
    q0 += __shfl_xor(q0, 16); q0 += __shfl_xor(q0, 32);
    s1 += __shfl_xor(s1, 16); s1 += __shfl_xor(s1, 32);
    q1 += __shfl_xor(q1, 16); q1 += __shfl_xor(q1, 32);
    if (l < 16) {
        atomicAdd(&ssum[oc0], s0); atomicAdd(&ssq[oc0], q0);
        atomicAdd(&ssum[oc1], s1); atomicAdd(&ssq[oc1], q1);
    }
    __syncthreads();
    if (tid < 64) {
        atomicAdd(&sumAcc[tid], ssum[tid]);
        atomicAdd(&sqAcc[tid], ssq[tid]);
    }
}

// ---------- conv3: in [NPOS][64] -> y3 [NPOS][2], f32 weights ----------
__global__ __launch_bounds__(256) void k_conv3(
    const __hip_bfloat16* __restrict__ in, const float* __restrict__ w,
    const float* __restrict__ bias, float* __restrict__ y3,
    float* __restrict__ sumAcc, float* __restrict__ sqAcc)
{
    __shared__ float wred[8];
    int tid = threadIdx.x;
    int p = blockIdx.x * 256 + tid;
    int z = p % 10, y = (p / 10) % 128, x = p / 1280;
    float a0 = bias[0], a1 = bias[1];
    for (int d = 0; d < 27; ++d) {
        int dx = d / 9 - 1, dy = (d / 3) % 3 - 1, dz = d % 3 - 1;
        if (!(((unsigned)(x + dx) < 128u) & ((unsigned)(y + dy) < 128u) & ((unsigned)(z + dz) < 10u)))
            continue;
        int off = (dx * 128 + dy) * 10 + dz;
        const short8* ip = (const short8*)(in + (size_t)(p + off) * 64);
#pragma unroll
        for (int cb = 0; cb < 8; ++cb) {
            short8 v = ip[cb];
#pragma unroll
            for (int j = 0; j < 8; ++j) {
                int ic = cb * 8 + j;
                float f = bfs2f(v[j]);
                a0 += f * w[(ic)*27 + d];
                a1 += f * w[(64 + ic) * 27 + d];
            }
        }
    }
    y3[(size_t)p * 2 + 0] = a0;
    y3[(size_t)p * 2 + 1] = a1;

    float s0 = a0, q0 = a0 * a0, s1 = a1, q1 = a1 * a1;
    for (int o = 32; o > 0; o >>= 1) {
        s0 += __shfl_down(s0, o); q0 += __shfl_down(q0, o);
        s1 += __shfl_down(s1, o); q1 += __shfl_down(q1, o);
    }
    int wv = tid >> 6;
    if ((tid & 63) == 0) { wred[wv] = s0; wred[4 + wv] = q0; }
    __syncthreads();
    if ((tid & 63) == 0 && wv == 0) {
        atomicAdd(&sumAcc[0], wred[0] + wred[1] + wred[2] + wred[3]);
        atomicAdd(&sqAcc[0], wred[4] + wred[5] + wred[6] + wred[7]);
    }
    __syncthreads();
    if ((tid & 63) == 0) { wred[wv] = s1; wred[4 + wv] = q1; }
    __syncthreads();
    if ((tid & 63) == 0 && wv == 0) {
        atomicAdd(&sumAcc[1], wred[0] + wred[1] + wred[2] + wred[3]);
        atomicAdd(&sqAcc[1], wred[4] + wred[5] + wred[6] + wred[7]);
    }
}

// ---------- vectorized bn+relu in place, layout [NPOS][64] ----------
__global__ void k_bnrelu_v(__hip_bfloat16* __restrict__ ybuf,
                           const float* __restrict__ stats, int base)
{
    const int C = 64;
    int nvec = NPOS * C / 8;
    short8* yv = (short8*)ybuf;
    for (int i = blockIdx.x * 256 + threadIdx.x; i < nvec; i += gridDim.x * 256) {
        int cb = (i & 7) * 8;
        short8 v = yv[i];
        short8 r;
#pragma unroll
        for (int j = 0; j < 8; ++j) {
            float f = bfs2f(v[j]) * stats[base + 2 * C + cb + j] + stats[base + 3 * C + cb + j];
            r[j] = f2bfs(fmaxf(f, 0.f));
        }
        yv[i] = r;
    }
}

// ------------------- gather + bn + relu + softmax -------------------
__global__ void k_out(const float* __restrict__ y3, const int* __restrict__ coords,
                      const float* __restrict__ stats, float* __restrict__ out)
{
    int n = blockIdx.x * 256 + threadIdx.x;
    if (n >= NVOX) return;
    int cx = coords[n * 4 + 1], cy = coords[n * 4 + 2], cz = coords[n * 4 + 3];
    int cell = (cx * GYD + cy) * GZD + cz;
    float a = fmaxf(y3[(size_t)cell * 2 + 0] * stats[S_C3 + 4] + stats[S_C3 + 6], 0.f);
    float b = fmaxf(y3[(size_t)cell * 2 + 1] * stats[S_C3 + 5] + stats[S_C3 + 7], 0.f);
    float m = fmaxf(a, b);
    float e0 = expf(a - m), e1 = expf(b - m);
    float inv = 1.f / (e0 + e1);
    out[n * 2 + 0] = e0 * inv;
    out[n * 2 + 1] = e1 * inv;
}

extern "C" void kernel_launch(void* const* d_in, const int* in_sizes, int n_in,
                              void* d_out, int out_size, void* d_ws, size_t ws_size,
                              hipStream_t stream)
{
    const float* vf     = (const float*)d_in[0];
    const int*   coords = (const int*)d_in[1];
    const float* w1  = (const float*)d_in[2];
    const float* b1  = (const float*)d_in[3];
    const float* g1  = (const float*)d_in[4];
    const float* be1 = (const float*)d_in[5];
    const float* w2  = (const float*)d_in[6];
    const float* b2  = (const float*)d_in[7];
    const float* g2  = (const float*)d_in[8];
    const float* be2 = (const float*)d_in[9];
    const float* w3  = (const float*)d_in[10];
    const float* b3  = (const float*)d_in[11];
    const float* g3  = (const float*)d_in[12];
    const float* be3 = (const float*)d_in[13];
    const float* c1w = (const float*)d_in[14];
    const float* c1b = (const float*)d_in[15];
    const float* c1g = (const float*)d_in[16];
    const float* c1be= (const float*)d_in[17];
    const float* c2w = (const float*)d_in[18];
    const float* c2b = (const float*)d_in[19];
    const float* c2g = (const float*)d_in[20];
    const float* c2be= (const float*)d_in[21];
    const float* c3w = (const float*)d_in[22];
    const float* c3b = (const float*)d_in[23];
    const float* c3g = (const float*)d_in[24];
    const float* c3be= (const float*)d_in[25];

    if (ws_size < WS_BYTES) return;

    char* base = (char*)d_ws;
    float* stats = (float*)(base + O_STATS);
    __hip_bfloat16* zp = (__hip_bfloat16*)(base + O_ZERO);
    int*   owner = (int*)(base + O_OWNER);
    float* h3max = (float*)(base + O_H3MAX);
    float* h3min = (float*)(base + O_H3MIN);
    __hip_bfloat16* wb1 = (__hip_bfloat16*)(base + O_WB1);
    __hip_bfloat16* wb2 = (__hip_bfloat16*)(base + O_WB2);
    __hip_bfloat16* dense = (__hip_bfloat16*)(base + O_DENSE);
    __hip_bfloat16* y1    = (__hip_bfloat16*)(base + O_Y1);
    __hip_bfloat16* y2    = (__hip_bfloat16*)(base + O_Y2);
    float* y3             = (float*)(base + O_Y3);

    hipMemsetAsync(stats, 0, STATS_FLOATS * sizeof(float), stream);
    hipMemsetAsync((void*)zp, 0, 256, stream);
    hipMemsetAsync(owner, 0xFF, (size_t)NPOS * sizeof(int), stream);
    hipMemsetAsync((void*)dense, 0, (size_t)NPOS * 128 * sizeof(__hip_bfloat16), stream);

    k_stats1<<<1024, 256, 0, stream>>>(vf, stats, w1, b1);
    k_finalize<<<1, 128, 0, stream>>>(stats, S_BN1, 16, 1.f / NTR, g1, be1);
    k_stats2<<<2048, 256, 0, stream>>>(vf, stats, w1, b1, w2, b2);
    k_finalize<<<1, 128, 0, stream>>>(stats, S_BN2, 64, 1.f / NTR, g2, be2);
    k_vfe3<<<2048, 256, 0, stream>>>(vf, stats, h3max, h3min, w1, b1, w2, b2, w3, b3);
    k_finalize<<<1, 128, 0, stream>>>(stats, S_BN3, 128, 1.f / NTR, g3, be3);
    k_owner<<<(NVOX + 255) / 256, 256, 0, stream>>>(coords, owner);
    k_scatter<<<NVOX, 128, 0, stream>>>(h3max, h3min, coords, owner, stats, dense);

    // weight relayout (after scatter: wb overlays h3max region)
    k_wcvt<<<(64 * 128 * 27 + 255) / 256, 256, 0, stream>>>(c1w, wb1, 64, 128);
    k_wcvt<<<(64 * 64 * 27 + 255) / 256, 256, 0, stream>>>(c2w, wb2, 64, 64);

    k_convm<128><<<NPOS / 64, 256, 0, stream>>>(dense, wb1, c1b, y1, zp,
                                                &stats[S_C1], &stats[S_C1 + 64]);
    k_finalize<<<1, 128, 0, stream>>>(stats, S_C1, 64, 1.f / NPOS, c1g, c1be);
    k_bnrelu_v<<<1024, 256, 0, stream>>>(y1, stats, S_C1);

    k_convm<64><<<NPOS / 64, 256, 0, stream>>>(y1, wb2, c2b, y2, zp,
                                               &stats[S_C2], &stats[S_C2 + 64]);
    k_finalize<<<1, 128, 0, stream>>>(stats, S_C2, 64, 1.f / NPOS, c2g, c2be);
    k_bnrelu_v<<<1024, 256, 0, stream>>>(y2, stats, S_C2);

    k_conv3<<<NPOS / 256, 256, 0, stream>>>(y2, c3w, c3b, y3,
                                            &stats[S_C3], &stats[S_C3 + 2]);
    k_finalize<<<1, 128, 0, stream>>>(stats, S_C3, 2, 1.f / NPOS, c3g, c3be);

    k_out<<<(NVOX + 255) / 256, 256, 0, stream>>>(y3, coords, stats, (float*)d_out);
}

// Round 9
// 1360.725 us; speedup vs baseline: 1.8168x; 1.2591x over previous
//
#include <hip/hip_runtime.h>
#include <hip/hip_bf16.h>
#include <cstddef>
#include <cstdint>

#define TT 35
#define NVOX 20000
#define NTR 700000
#define FIN 7
#define GXD 128
#define GYD 128
#define GZD 10
#define NPOS 163840
#define BNEPS 1e-5f

// stats layout (float offsets): per group {sum[C], sq[C], scale[C], shift[C]}
#define S_BN1 0
#define S_BN2 64
#define S_BN3 320
#define S_C1  832
#define S_C2  1088
#define S_C3  1344
#define STATS_FLOATS 2048

// byte offsets inside ws (unchanged total: 84,062,208 B)
#define O_STATS 0ull
#define O_ZERO  8192ull           // 256 B zero page
#define O_OWNER 12288ull          // 163840*4
#define O_H3MAX 667648ull         // 20000*128*4
#define O_G     O_H3MAX           // 1056 f32 Gram+s (dead before h3max written)
#define O_H3MIN 10907648ull       // 20000*128*4
#define O_WB1   667648ull         // bf16 27*64*128 (after scatter, h3max dead)
#define O_WB2   1110016ull        // bf16 27*64*64
#define O_DENSE 21147648ull       // bf16 [NPOS][128]
#define O_PC    O_DENSE           // bf16 [NTR][32] (dead before dense memset)
#define O_MKF   67284992ull       // f32 [NTR] mask (dead before conv1 writes y1)
#define O_Y1    63090688ull       // bf16 [NPOS][64]
#define O_Y2    O_DENSE           // bf16 [NPOS][64]
#define O_Y3    O_H3MIN           // f32 [NPOS][2]
#define WS_BYTES 84062208ull

typedef __attribute__((ext_vector_type(8))) short short8;
typedef __attribute__((ext_vector_type(4))) float f32x4;

__device__ __forceinline__ float bf2f(__hip_bfloat16 x) { return __bfloat162float(x); }
__device__ __forceinline__ __hip_bfloat16 f2bf(float x) { return __float2bfloat16(x); }
__device__ __forceinline__ float bfs2f(short s) {
    union { unsigned u; float f; } cv; cv.u = ((unsigned)(unsigned short)s) << 16; return cv.f;
}
__device__ __forceinline__ short f2bfs(float f) {
    __hip_bfloat16 h = __float2bfloat16(f);
    return *(short*)&h;
}

// ------------------- BN1 stats -------------------
__global__ __launch_bounds__(256) void k_stats1(
    const float* __restrict__ vf, float* __restrict__ stats,
    const float* __restrict__ w1, const float* __restrict__ b1)
{
    __shared__ float w1s[112], b1s[16];
    __shared__ float ssum[16], ssq[16];
    int tid = threadIdx.x;
    for (int i = tid; i < 112; i += 256) w1s[i] = w1[i];
    if (tid < 16) { b1s[tid] = b1[tid]; ssum[tid] = 0.f; ssq[tid] = 0.f; }
    __syncthreads();

    float lsum[16], lsq[16];
#pragma unroll
    for (int u = 0; u < 16; ++u) { lsum[u] = 0.f; lsq[u] = 0.f; }

    for (int r = blockIdx.x * 256 + tid; r < NTR; r += gridDim.x * 256) {
        float v[FIN];
#pragma unroll
        for (int f = 0; f < FIN; ++f) v[f] = vf[(size_t)r * FIN + f];
#pragma unroll
        for (int u = 0; u < 16; ++u) {
            float h = b1s[u];
#pragma unroll
            for (int f = 0; f < FIN; ++f) h += v[f] * w1s[f * 16 + u];
            lsum[u] += h; lsq[u] += h * h;
        }
    }
#pragma unroll
    for (int u = 0; u < 16; ++u) {
        float a = lsum[u], b = lsq[u];
        for (int off = 32; off > 0; off >>= 1) {
            a += __shfl_down(a, off);
            b += __shfl_down(b, off);
        }
        if ((tid & 63) == 0) { atomicAdd(&ssum[u], a); atomicAdd(&ssq[u], b); }
    }
    __syncthreads();
    if (tid < 16) {
        atomicAdd(&stats[S_BN1 + tid], ssum[tid]);
        atomicAdd(&stats[S_BN1 + 16 + tid], ssq[tid]);
    }
}

// ------------------- finalize BN params -------------------
__global__ void k_finalize(float* __restrict__ stats, int base, int C, float invM,
                           const float* __restrict__ g, const float* __restrict__ be)
{
    int i = threadIdx.x;
    if (i < C) {
        float mean = stats[base + i] * invM;
        float var  = stats[base + C + i] * invM - mean * mean;
        float sc = g[i] * rsqrtf(var + BNEPS);
        stats[base + 2 * C + i] = sc;
        stats[base + 3 * C + i] = be[i] - mean * sc;
    }
}

// stage-1 (h1->bn1->relu, laf, mask, pwcf into LDS pc[TT*32])
__device__ __forceinline__ void stage1(
    int tid, int n, const float* __restrict__ vf,
    const float* w1s, const float* b1s, const float* sc1, const float* sh1,
    float* pwf, float* laf, float* mk, float* pc)
{
    {
        int u = tid & 15, tg = tid >> 4;
        for (int t = tg; t < TT; t += 16) {
            const float* vr = vf + (size_t)(n * TT + t) * FIN;
            float vv[FIN];
#pragma unroll
            for (int f = 0; f < FIN; ++f) vv[f] = vr[f];
            float h = b1s[u];
#pragma unroll
            for (int f = 0; f < FIN; ++f) h += vv[f] * w1s[f * 16 + u];
            pwf[t * 16 + u] = fmaxf(h * sc1[u] + sh1[u], 0.f);
            if (u == 0) {
                float mx = vv[0];
#pragma unroll
                for (int f = 1; f < FIN; ++f) mx = fmaxf(mx, vv[f]);
                mk[t] = (mx != 0.f) ? 1.f : 0.f;
            }
        }
    }
    __syncthreads();
    if (tid < 16) {   // laf = max over t, PRE-mask
        float m = pwf[tid];
        for (int t = 1; t < TT; ++t) m = fmaxf(m, pwf[t * 16 + tid]);
        laf[tid] = m;
    }
    __syncthreads();
    {
        int c = tid & 31, tg = tid >> 5;
        for (int t = tg; t < TT; t += 8)
            pc[t * 32 + c] = (c < 16 ? pwf[t * 16 + c] : laf[c - 16]) * mk[t];
    }
    __syncthreads();
}

// ---- k_pc: stage1 once; store pc (bf16) + mask; accumulate Gram G and colsum s ----
__global__ __launch_bounds__(256) void k_pc(
    const float* __restrict__ vf, const float* __restrict__ stats,
    __hip_bfloat16* __restrict__ pcg, float* __restrict__ mkg,
    float* __restrict__ Gg,
    const float* __restrict__ w1, const float* __restrict__ b1)
{
    __shared__ float w1s[112], b1s[16], sc1[16], sh1[16];
    __shared__ float pwf[TT * 16], laf[16], mk[TT];
    __shared__ __align__(16) float pc[TT * 32];
    int tid = threadIdx.x;
    for (int i = tid; i < 112; i += 256) w1s[i] = w1[i];
    if (tid < 16) {
        b1s[tid] = b1[tid];
        sc1[tid] = stats[S_BN1 + 32 + tid];
        sh1[tid] = stats[S_BN1 + 48 + tid];
    }
    __syncthreads();

    int gi = tid >> 3, gj = (tid & 7) * 4;
    float ga0 = 0.f, ga1 = 0.f, ga2 = 0.f, ga3 = 0.f;
    float sacc = 0.f;

    for (int n = blockIdx.x; n < NVOX; n += gridDim.x) {
        stage1(tid, n, vf, w1s, b1s, sc1, sh1, pwf, laf, mk, pc);
        // store pc bf16 + mask
        if (tid < 140) {
            int t = tid >> 2, part = tid & 3;
            short8 v;
#pragma unroll
            for (int j = 0; j < 8; ++j) v[j] = f2bfs(pc[t * 32 + part * 8 + j]);
            *(short8*)(pcg + ((size_t)n * TT + t) * 32 + part * 8) = v;
        }
        if (tid < TT) mkg[n * TT + tid] = mk[tid];
        // Gram accumulation: thread owns (gi, gj..gj+3)
        for (int t = 0; t < TT; ++t) {
            float xi = pc[t * 32 + gi];
            f32x4 xj = *(const f32x4*)&pc[t * 32 + gj];
            ga0 += xi * xj[0]; ga1 += xi * xj[1];
            ga2 += xi * xj[2]; ga3 += xi * xj[3];
        }
        if (tid < 32) {
            float a = 0.f;
            for (int t = 0; t < TT; ++t) a += pc[t * 32 + tid];
            sacc += a;
        }
        __syncthreads();   // protect mk/pc before next stage1 rewrite
    }
    atomicAdd(&Gg[gi * 32 + gj + 0], ga0);
    atomicAdd(&Gg[gi * 32 + gj + 1], ga1);
    atomicAdd(&Gg[gi * 32 + gj + 2], ga2);
    atomicAdd(&Gg[gi * 32 + gj + 3], ga3);
    if (tid < 32) atomicAdd(&Gg[1024 + tid], sacc);
}

// ---- BN2 scale/shift from Gram: sum h2 = s.w + N b ; sum h2^2 = w'Gw + 2b(s.w) + N b^2 ----
__global__ void k_bn2g(const float* __restrict__ Gg,
                       const float* __restrict__ w2, const float* __restrict__ b2,
                       const float* __restrict__ g2, const float* __restrict__ be2,
                       float* __restrict__ stats)
{
    int u = threadIdx.x;
    if (u >= 64) return;
    float wc[32];
#pragma unroll
    for (int c = 0; c < 32; ++c) wc[c] = w2[c * 64 + u];
    float dot = 0.f;
#pragma unroll
    for (int c = 0; c < 32; ++c) dot += Gg[1024 + c] * wc[c];
    float quad = 0.f;
    for (int c = 0; c < 32; ++c) {
        float a = 0.f;
#pragma unroll
        for (int c2 = 0; c2 < 32; ++c2) a += Gg[c * 32 + c2] * wc[c2];
        quad += wc[c] * a;
    }
    float b = b2[u];
    float N = (float)NTR;
    float mean = (dot + N * b) / N;
    float q = quad + 2.f * b * dot + N * b * b;
    float var = q / N - mean * mean;
    float sc = g2[u] * rsqrtf(var + BNEPS);
    stats[S_BN2 + 128 + u] = sc;
    stats[S_BN2 + 192 + u] = be2[u] - mean * sc;
}

// ---- MFMA VFE2+FCN: pc -> h2 -> pc2 -> h3 ; h3 max/min + BN3 sums ----
// 256 thr = 4 waves; wave w: h2 cols w*16..+15, h3 cols {2w,2w+1}*16..
__global__ __launch_bounds__(256) void k_vfe3m(
    const __hip_bfloat16* __restrict__ pcg, const float* __restrict__ mkg,
    float* __restrict__ stats,
    float* __restrict__ h3max, float* __restrict__ h3min,
    const float* __restrict__ w2, const float* __restrict__ b2,
    const float* __restrict__ w3, const float* __restrict__ b3,
    const __hip_bfloat16* __restrict__ zp)
{
    __shared__ __align__(16) short pc2s[48 * 128];  // bf16, XOR-swizzled rows
    __shared__ float mkan[48];
    int tid = threadIdx.x;
    int l = tid & 63, w = tid >> 6;
    int lr = l & 15, lk = l >> 4;
    int cw2 = w * 16 + lr;

    // wave-invariant B fragments (k = lk*8+j convention, col = lr + tile*16)
    short8 w2f;
#pragma unroll
    for (int j = 0; j < 8; ++j) w2f[j] = f2bfs(w2[(lk * 8 + j) * 64 + cw2]);
    int c3[2] = { (2 * w) * 16 + lr, (2 * w + 1) * 16 + lr };
    short8 w3f[2][4];
#pragma unroll
    for (int ni = 0; ni < 2; ++ni)
#pragma unroll
        for (int ks = 0; ks < 4; ++ks)
#pragma unroll
            for (int j = 0; j < 8; ++j)
                w3f[ni][ks][j] = f2bfs(w3[(ks * 32 + lk * 8 + j) * 128 + c3[ni]]);

    float sc2c = stats[S_BN2 + 128 + cw2], sh2c = stats[S_BN2 + 192 + cw2];
    float b2c = b2[cw2];
    float b3c[2] = { b3[c3[0]], b3[c3[1]] };
    float s3a[2] = { 0.f, 0.f }, q3a[2] = { 0.f, 0.f };

    if (tid < 48) mkan[tid] = 0.f;   // rows 35..47 stay 0 forever
    __syncthreads();

    char* pb = (char*)pc2s;
    for (int n = blockIdx.x; n < NVOX; n += gridDim.x) {
        if (tid < TT) mkan[tid] = mkg[n * TT + tid];
        // ---- h2 MFMA ----
        f32x4 hacc[3];
#pragma unroll
        for (int mt = 0; mt < 3; ++mt) {
            int t = mt * 16 + lr;
            const short8* ap = (t < TT)
                ? (const short8*)(pcg + ((size_t)n * TT + t) * 32 + lk * 8)
                : (const short8*)zp;
            short8 a = *ap;
            hacc[mt] = { b2c, b2c, b2c, b2c };
            hacc[mt] = __builtin_amdgcn_mfma_f32_16x16x32_bf16(a, w2f, hacc[mt], 0, 0, 0);
        }
        // bn2 + relu (thread holds col cw2, rows mt*16 + lk*4 + r)
        float pw2[3][4];
#pragma unroll
        for (int mt = 0; mt < 3; ++mt)
#pragma unroll
            for (int r = 0; r < 4; ++r)
                pw2[mt][r] = fmaxf(hacc[mt][r] * sc2c + sh2c, 0.f);
        // laf2 = max over t<35 (values >= 0)
        float lm = 0.f;
#pragma unroll
        for (int mt = 0; mt < 2; ++mt)
#pragma unroll
            for (int r = 0; r < 4; ++r) lm = fmaxf(lm, pw2[mt][r]);
        if (lk == 0) {
#pragma unroll
            for (int r = 0; r < 3; ++r) lm = fmaxf(lm, pw2[2][r]);
        }
        lm = fmaxf(lm, __shfl_xor(lm, 16));
        lm = fmaxf(lm, __shfl_xor(lm, 32));
        __syncthreads();   // (a) mkan ready; prev h3 reads done
        // ---- write pc2 (swizzled bf16) ----
#pragma unroll
        for (int mt = 0; mt < 3; ++mt)
#pragma unroll
            for (int r = 0; r < 4; ++r) {
                int t = mt * 16 + lk * 4 + r;
                float mv = mkan[t];
                int swz = (t & 7) << 4;
                *(short*)(pb + t * 256 + ((2 * cw2) ^ swz)) = f2bfs(pw2[mt][r] * mv);
                *(short*)(pb + t * 256 + ((2 * (64 + cw2)) ^ swz)) = f2bfs(lm * mv);
            }
        __syncthreads();   // (b) pc2 ready
        // ---- h3 MFMA ----
        f32x4 acc3[2][3];
#pragma unroll
        for (int ni = 0; ni < 2; ++ni)
#pragma unroll
            for (int mt = 0; mt < 3; ++mt)
                acc3[ni][mt] = { b3c[ni], b3c[ni], b3c[ni], b3c[ni] };
#pragma unroll
        for (int mt = 0; mt < 3; ++mt) {
            int t = mt * 16 + lr;
            int swz = (t & 7) << 4;
            short8 a[4];
#pragma unroll
            for (int ks = 0; ks < 4; ++ks)
                a[ks] = *(const short8*)(pb + t * 256 + ((2 * (ks * 32 + lk * 8)) ^ swz));
#pragma unroll
            for (int ni = 0; ni < 2; ++ni)
#pragma unroll
                for (int ks = 0; ks < 4; ++ks)
                    acc3[ni][mt] = __builtin_amdgcn_mfma_f32_16x16x32_bf16(
                        a[ks], w3f[ni][ks], acc3[ni][mt], 0, 0, 0);
        }
        // ---- per-col max/min/sum/sq over t ----
#pragma unroll
        for (int ni = 0; ni < 2; ++ni) {
            float mx = -1e30f, mn = 1e30f, s = 0.f, q = 0.f;
#pragma unroll
            for (int mt = 0; mt < 3; ++mt)
#pragma unroll
                for (int r = 0; r < 4; ++r) {
                    int t = mt * 16 + lk * 4 + r;
                    if (t < TT) {
                        float h = acc3[ni][mt][r];
                        mx = fmaxf(mx, h); mn = fminf(mn, h);
                        s += h; q += h * h;
                    }
                }
            mx = fmaxf(mx, __shfl_xor(mx, 16)); mx = fmaxf(mx, __shfl_xor(mx, 32));
            mn = fminf(mn, __shfl_xor(mn, 16)); mn = fminf(mn, __shfl_xor(mn, 32));
            s += __shfl_xor(s, 16); s += __shfl_xor(s, 32);
            q += __shfl_xor(q, 16); q += __shfl_xor(q, 32);
            if (l < 16) {
                h3max[(size_t)n * 128 + c3[ni]] = mx;
                h3min[(size_t)n * 128 + c3[ni]] = mn;
                s3a[ni] += s; q3a[ni] += q;
            }
        }
    }
    if (l < 16) {
#pragma unroll
        for (int ni = 0; ni < 2; ++ni) {
            atomicAdd(&stats[S_BN3 + c3[ni]], s3a[ni]);
            atomicAdd(&stats[S_BN3 + 128 + c3[ni]], q3a[ni]);
        }
    }
}

// ------------------- owner resolution (last index wins) -------------------
__global__ void k_owner(const int* __restrict__ coords, int* __restrict__ owner)
{
    int n = blockIdx.x * 256 + threadIdx.x;
    if (n >= NVOX) return;
    int cx = coords[n * 4 + 1], cy = coords[n * 4 + 2], cz = coords[n * 4 + 3];
    atomicMax(&owner[(cx * GYD + cy) * GZD + cz], n);
}

// ---------- bn3+relu via max/min, scatter into dense [NPOS][128] bf16 ----------
__global__ __launch_bounds__(128) void k_scatter(
    const float* __restrict__ h3max, const float* __restrict__ h3min,
    const int* __restrict__ coords, const int* __restrict__ owner,
    const float* __restrict__ stats, __hip_bfloat16* __restrict__ dense)
{
    int n = blockIdx.x, k = threadIdx.x;
    int cx = coords[n * 4 + 1], cy = coords[n * 4 + 2], cz = coords[n * 4 + 3];
    int cell = (cx * GYD + cy) * GZD + cz;
    if (owner[cell] != n) return;
    float sc = stats[S_BN3 + 256 + k], sh = stats[S_BN3 + 384 + k];
    float h = (sc >= 0.f) ? h3max[(size_t)n * 128 + k] : h3min[(size_t)n * 128 + k];
    dense[(size_t)cell * 128 + k] = f2bf(fmaxf(h * sc + sh, 0.f));
}

// ---------- weight relayout: src [OC][IC][27] f32 -> dst [27][OC][IC] bf16 ----------
__global__ void k_wcvt(const float* __restrict__ src, __hip_bfloat16* __restrict__ dst,
                       int OC, int IC)
{
    int i = blockIdx.x * 256 + threadIdx.x;
    int total = OC * IC * 27;
    if (i >= total) return;
    int d = i / (OC * IC);
    int rem = i - d * (OC * IC);
    int o = rem / IC, ic = rem - o * IC;
    dst[i] = f2bf(src[(o * IC + ic) * 27 + d]);
}

// ---------- MFMA implicit-GEMM 3x3x3 conv: in [NPOS][IC] -> out [NPOS][64] ----------
template <int IC>
__global__ __launch_bounds__(256) void k_convm(
    const __hip_bfloat16* __restrict__ in, const __hip_bfloat16* __restrict__ wb,
    const float* __restrict__ bias, __hip_bfloat16* __restrict__ outp,
    const __hip_bfloat16* __restrict__ zp,
    float* __restrict__ sumAcc, float* __restrict__ sqAcc)
{
    constexpr int KS = IC / 32;
    __shared__ float ssum[64], ssq[64];
    int tid = threadIdx.x;
    if (tid < 64) { ssum[tid] = 0.f; ssq[tid] = 0.f; }
    __syncthreads();

    int l = tid & 63, wave = tid >> 6;
    int wm = wave >> 1, wn = wave & 1;
    int lr = l & 15, lk = l >> 4;

    int pbase = blockIdx.x * 64;
    int p0 = pbase + wm * 32 + lr;
    int p1 = p0 + 16;
    int z0 = p0 % 10, y0 = (p0 / 10) % 128, x0 = p0 / 1280;
    int z1 = p1 % 10, y1c = (p1 / 10) % 128, x1 = p1 / 1280;

    int oc0 = wn * 32 + lr;
    int oc1 = oc0 + 16;
    const short8* wrow0 = (const short8*)(wb + (size_t)oc0 * IC + lk * 8);
    const short8* wrow1 = (const short8*)(wb + (size_t)oc1 * IC + lk * 8);
    const int tapstride = 64 * IC / 8;

    float bb0 = bias[oc0], bb1 = bias[oc1];
    f32x4 acc[2][2];
#pragma unroll
    for (int t = 0; t < 2; ++t) {
        acc[t][0] = { bb0, bb0, bb0, bb0 };
        acc[t][1] = { bb1, bb1, bb1, bb1 };
    }

    for (int d = 0; d < 27; ++d) {
        int dx = d / 9 - 1, dy = (d / 3) % 3 - 1, dz = d % 3 - 1;
        int off = (dx * 128 + dy) * 10 + dz;
        bool v0 = ((unsigned)(x0 + dx) < 128u) & ((unsigned)(y0 + dy) < 128u) & ((unsigned)(z0 + dz) < 10u);
        bool v1 = ((unsigned)(x1 + dx) < 128u) & ((unsigned)(y1c + dy) < 128u) & ((unsigned)(z1 + dz) < 10u);
        const short8* a0p = v0 ? (const short8*)(in + (size_t)(p0 + off) * IC + lk * 8)
                               : (const short8*)zp;
        const short8* a1p = v1 ? (const short8*)(in + (size_t)(p1 + off) * IC + lk * 8)
                               : (const short8*)zp;
        const short8* b0p = wrow0 + (size_t)d * tapstride;
        const short8* b1p = wrow1 + (size_t)d * tapstride;
#pragma unroll
        for (int k = 0; k < KS; ++k) {
            short8 a0 = a0p[k * 4];
            short8 a1 = a1p[k * 4];
            short8 b0 = b0p[k * 4];
            short8 b1 = b1p[k * 4];
            acc[0][0] = __builtin_amdgcn_mfma_f32_16x16x32_bf16(a0, b0, acc[0][0], 0, 0, 0);
            acc[0][1] = __builtin_amdgcn_mfma_f32_16x16x32_bf16(a0, b1, acc[0][1], 0, 0, 0);
            acc[1][0] = __builtin_amdgcn_mfma_f32_16x16x32_bf16(a1, b0, acc[1][0], 0, 0, 0);
            acc[1][1] = __builtin_amdgcn_mfma_f32_16x16x32_bf16(a1, b1, acc[1][1], 0, 0, 0);
        }
    }

    float s0 = 0.f, q0 = 0.f, s1 = 0.f, q1 = 0.f;
#pragma unroll
    for (int t = 0; t < 2; ++t) {
#pragma unroll
        for (int r = 0; r < 4; ++r) {
            int prow = pbase + wm * 32 + t * 16 + lk * 4 + r;
            float v0c = acc[t][0][r], v1c = acc[t][1][r];
            outp[(size_t)prow * 64 + oc0] = f2bf(v0c);
            outp[(size_t)prow * 64 + oc1] = f2bf(v1c);
            s0 += v0c; q0 += v0c * v0c;
            s1 += v1c; q1 += v1c * v1c;
        }
    }
    s0 += __shfl_xor(s0, 16); s0 += __shfl_xor(s0, 32);
    q0 += __shfl_xor(q0, 16); q0 += __shfl_xor(q0, 32);
    s1 += __shfl_xor(s1, 16); s1 += __shfl_xor(s1, 32);
    q1 += __shfl_xor(q1, 16); q1 += __shfl_xor(q1, 32);
    if (l < 16) {
        atomicAdd(&ssum[oc0], s0); atomicAdd(&ssq[oc0], q0);
        atomicAdd(&ssum[oc1], s1); atomicAdd(&ssq[oc1], q1);
    }
    __syncthreads();
    if (tid < 64) {
        atomicAdd(&sumAcc[tid], ssum[tid]);
        atomicAdd(&sqAcc[tid], ssq[tid]);
    }
}

// ---------- conv3: in [NPOS][64] -> y3 [NPOS][2] ----------
__global__ __launch_bounds__(256) void k_conv3(
    const __hip_bfloat16* __restrict__ in, const float* __restrict__ w,
    const float* __restrict__ bias, float* __restrict__ y3,
    float* __restrict__ sumAcc, float* __restrict__ sqAcc)
{
    __shared__ float wred[8];
    int tid = threadIdx.x;
    int p = blockIdx.x * 256 + tid;
    int z = p % 10, y = (p / 10) % 128, x = p / 1280;
    float a0 = bias[0], a1 = bias[1];
    for (int d = 0; d < 27; ++d) {
        int dx = d / 9 - 1, dy = (d / 3) % 3 - 1, dz = d % 3 - 1;
        if (!(((unsigned)(x + dx) < 128u) & ((unsigned)(y + dy) < 128u) & ((unsigned)(z + dz) < 10u)))
            continue;
        int off = (dx * 128 + dy) * 10 + dz;
        const short8* ip = (const short8*)(in + (size_t)(p + off) * 64);
#pragma unroll
        for (int cb = 0; cb < 8; ++cb) {
            short8 v = ip[cb];
#pragma unroll
            for (int j = 0; j < 8; ++j) {
                int ic = cb * 8 + j;
                float f = bfs2f(v[j]);
                a0 += f * w[(ic) * 27 + d];
                a1 += f * w[(64 + ic) * 27 + d];
            }
        }
    }
    y3[(size_t)p * 2 + 0] = a0;
    y3[(size_t)p * 2 + 1] = a1;

    float s0 = a0, q0 = a0 * a0, s1 = a1, q1 = a1 * a1;
    for (int o = 32; o > 0; o >>= 1) {
        s0 += __shfl_down(s0, o); q0 += __shfl_down(q0, o);
        s1 += __shfl_down(s1, o); q1 += __shfl_down(q1, o);
    }
    int wv = tid >> 6;
    if ((tid & 63) == 0) { wred[wv] = s0; wred[4 + wv] = q0; }
    __syncthreads();
    if ((tid & 63) == 0 && wv == 0) {
        atomicAdd(&sumAcc[0], wred[0] + wred[1] + wred[2] + wred[3]);
        atomicAdd(&sqAcc[0], wred[4] + wred[5] + wred[6] + wred[7]);
    }
    __syncthreads();
    if ((tid & 63) == 0) { wred[wv] = s1; wred[4 + wv] = q1; }
    __syncthreads();
    if ((tid & 63) == 0 && wv == 0) {
        atomicAdd(&sumAcc[1], wred[0] + wred[1] + wred[2] + wred[3]);
        atomicAdd(&sqAcc[1], wred[4] + wred[5] + wred[6] + wred[7]);
    }
}

// ---------- vectorized bn+relu in place, layout [NPOS][64] ----------
__global__ void k_bnrelu_v(__hip_bfloat16* __restrict__ ybuf,
                           const float* __restrict__ stats, int base)
{
    const int C = 64;
    int nvec = NPOS * C / 8;
    short8* yv = (short8*)ybuf;
    for (int i = blockIdx.x * 256 + threadIdx.x; i < nvec; i += gridDim.x * 256) {
        int cb = (i & 7) * 8;
        short8 v = yv[i];
        short8 r;
#pragma unroll
        for (int j = 0; j < 8; ++j) {
            float f = bfs2f(v[j]) * stats[base + 2 * C + cb + j] + stats[base + 3 * C + cb + j];
            r[j] = f2bfs(fmaxf(f, 0.f));
        }
        yv[i] = r;
    }
}

// ------------------- gather + bn + relu + softmax -------------------
__global__ void k_out(const float* __restrict__ y3, const int* __restrict__ coords,
                      const float* __restrict__ stats, float* __restrict__ out)
{
    int n = blockIdx.x * 256 + threadIdx.x;
    if (n >= NVOX) return;
    int cx = coords[n * 4 + 1], cy = coords[n * 4 + 2], cz = coords[n * 4 + 3];
    int cell = (cx * GYD + cy) * GZD + cz;
    float a = fmaxf(y3[(size_t)cell * 2 + 0] * stats[S_C3 + 4] + stats[S_C3 + 6], 0.f);
    float b = fmaxf(y3[(size_t)cell * 2 + 1] * stats[S_C3 + 5] + stats[S_C3 + 7], 0.f);
    float m = fmaxf(a, b);
    float e0 = expf(a - m), e1 = expf(b - m);
    float inv = 1.f / (e0 + e1);
    out[n * 2 + 0] = e0 * inv;
    out[n * 2 + 1] = e1 * inv;
}

extern "C" void kernel_launch(void* const* d_in, const int* in_sizes, int n_in,
                              void* d_out, int out_size, void* d_ws, size_t ws_size,
                              hipStream_t stream)
{
    const float* vf     = (const float*)d_in[0];
    const int*   coords = (const int*)d_in[1];
    const float* w1  = (const float*)d_in[2];
    const float* b1  = (const float*)d_in[3];
    const float* g1  = (const float*)d_in[4];
    const float* be1 = (const float*)d_in[5];
    const float* w2  = (const float*)d_in[6];
    const float* b2  = (const float*)d_in[7];
    const float* g2  = (const float*)d_in[8];
    const float* be2 = (const float*)d_in[9];
    const float* w3  = (const float*)d_in[10];
    const float* b3  = (const float*)d_in[11];
    const float* g3  = (const float*)d_in[12];
    const float* be3 = (const float*)d_in[13];
    const float* c1w = (const float*)d_in[14];
    const float* c1b = (const float*)d_in[15];
    const float* c1g = (const float*)d_in[16];
    const float* c1be= (const float*)d_in[17];
    const float* c2w = (const float*)d_in[18];
    const float* c2b = (const float*)d_in[19];
    const float* c2g = (const float*)d_in[20];
    const float* c2be= (const float*)d_in[21];
    const float* c3w = (const float*)d_in[22];
    const float* c3b = (const float*)d_in[23];
    const float* c3g = (const float*)d_in[24];
    const float* c3be= (const float*)d_in[25];

    if (ws_size < WS_BYTES) return;

    char* base = (char*)d_ws;
    float* stats = (float*)(base + O_STATS);
    __hip_bfloat16* zp = (__hip_bfloat16*)(base + O_ZERO);
    int*   owner = (int*)(base + O_OWNER);
    float* Gg    = (float*)(base + O_G);
    float* h3max = (float*)(base + O_H3MAX);
    float* h3min = (float*)(base + O_H3MIN);
    __hip_bfloat16* wb1 = (__hip_bfloat16*)(base + O_WB1);
    __hip_bfloat16* wb2 = (__hip_bfloat16*)(base + O_WB2);
    __hip_bfloat16* pcg = (__hip_bfloat16*)(base + O_PC);
    float* mkg          = (float*)(base + O_MKF);
    __hip_bfloat16* dense = (__hip_bfloat16*)(base + O_DENSE);
    __hip_bfloat16* y1    = (__hip_bfloat16*)(base + O_Y1);
    __hip_bfloat16* y2    = (__hip_bfloat16*)(base + O_Y2);
    float* y3             = (float*)(base + O_Y3);

    hipMemsetAsync(stats, 0, STATS_FLOATS * sizeof(float), stream);
    hipMemsetAsync((void*)zp, 0, 256, stream);
    hipMemsetAsync(owner, 0xFF, (size_t)NPOS * sizeof(int), stream);
    hipMemsetAsync(Gg, 0, 1056 * sizeof(float), stream);

    k_stats1<<<1024, 256, 0, stream>>>(vf, stats, w1, b1);
    k_finalize<<<1, 128, 0, stream>>>(stats, S_BN1, 16, 1.f / NTR, g1, be1);
    k_pc<<<2048, 256, 0, stream>>>(vf, stats, pcg, mkg, Gg, w1, b1);
    k_bn2g<<<1, 64, 0, stream>>>(Gg, w2, b2, g2, be2, stats);
    k_vfe3m<<<1024, 256, 0, stream>>>(pcg, mkg, stats, h3max, h3min,
                                      w2, b2, w3, b3, zp);
    k_finalize<<<1, 128, 0, stream>>>(stats, S_BN3, 128, 1.f / NTR, g3, be3);
    k_owner<<<(NVOX + 255) / 256, 256, 0, stream>>>(coords, owner);
    hipMemsetAsync((void*)dense, 0, (size_t)NPOS * 128 * sizeof(__hip_bfloat16), stream);
    k_scatter<<<NVOX, 128, 0, stream>>>(h3max, h3min, coords, owner, stats, dense);

    k_wcvt<<<(64 * 128 * 27 + 255) / 256, 256, 0, stream>>>(c1w, wb1, 64, 128);
    k_wcvt<<<(64 * 64 * 27 + 255) / 256, 256, 0, stream>>>(c2w, wb2, 64, 64);

    k_convm<128><<<NPOS / 64, 256, 0, stream>>>(dense, wb1, c1b, y1, zp,
                                                &stats[S_C1], &stats[S_C1 + 64]);
    k_finalize<<<1, 128, 0, stream>>>(stats, S_C1, 64, 1.f / NPOS, c1g, c1be);
    k_bnrelu_v<<<1024, 256, 0, stream>>>(y1, stats, S_C1);

    k_convm<64><<<NPOS / 64, 256, 0, stream>>>(y1, wb2, c2b, y2, zp,
                                               &stats[S_C2], &stats[S_C2 + 64]);
    k_finalize<<<1, 128, 0, stream>>>(stats, S_C2, 64, 1.f / NPOS, c2g, c2be);
    k_bnrelu_v<<<1024, 256, 0, stream>>>(y2, stats, S_C2);

    k_conv3<<<NPOS / 256, 256, 0, stream>>>(y2, c3w, c3b, y3,
                                            &stats[S_C3], &stats[S_C3 + 2]);
    k_finalize<<<1, 128, 0, stream>>>(stats, S_C3, 2, 1.f / NPOS, c3g, c3be);

    k_out<<<(NVOX + 255) / 256, 256, 0, stream>>>(y3, coords, stats, (float*)d_out);
}

// Round 11
// 864.094 us; speedup vs baseline: 2.8610x; 1.5747x over previous
//
#include <hip/hip_runtime.h>
#include <hip/hip_bf16.h>
#include <cstddef>
#include <cstdint>

#define TT 35
#define NVOX 20000
#define NTR 700000
#define FIN 7
#define GXD 128
#define GYD 128
#define GZD 10
#define NPOS 163840
#define BNEPS 1e-5f

// stats layout (float offsets): per group {sum[C], sq[C], scale[C], shift[C]}
#define S_BN1 0
#define S_BN2 64
#define S_BN3 320
#define S_C1  832
#define S_C2  1088
#define S_C3  1344
#define STATS_FLOATS 2048

// byte offsets inside ws (unchanged total: 84,062,208 B)
#define O_STATS 0ull
#define O_ZERO  8192ull           // 256 B zero page
#define O_OWNER 12288ull          // 163840*4
#define O_H3MAX 667648ull         // 20000*128*4
#define O_G     O_H3MAX           // 1056 f32 Gram+s (dead before h3max written)
#define O_H3MIN 10907648ull       // 20000*128*4
#define O_WB1   667648ull         // bf16 27*64*128 (after scatter, h3max dead)
#define O_WB2   1110016ull        // bf16 27*64*64
#define O_DENSE 21147648ull       // bf16 [NPOS][128]
#define O_PC    O_DENSE           // bf16 [NTR][32] (dead before dense memset)
#define O_MKF   67284992ull       // f32 [NTR] mask (dead before conv1 writes y1)
#define O_Y1    63090688ull       // bf16 [NPOS][64]
#define O_Y2    O_DENSE           // bf16 [NPOS][64]
#define O_Y3    O_H3MIN           // f32 [NPOS][2]
#define WS_BYTES 84062208ull

typedef __attribute__((ext_vector_type(8))) short short8;
typedef __attribute__((ext_vector_type(4))) float f32x4;
typedef __attribute__((ext_vector_type(4))) int int4v;

__device__ __forceinline__ float bf2f(__hip_bfloat16 x) { return __bfloat162float(x); }
__device__ __forceinline__ __hip_bfloat16 f2bf(float x) { return __float2bfloat16(x); }
__device__ __forceinline__ float bfs2f(short s) {
    union { unsigned u; float f; } cv; cv.u = ((unsigned)(unsigned short)s) << 16; return cv.f;
}
__device__ __forceinline__ short f2bfs(float f) {
    __hip_bfloat16 h = __float2bfloat16(f);
    return *(short*)&h;
}

// ------------------- BN1 stats -------------------
__global__ __launch_bounds__(256) void k_stats1(
    const float* __restrict__ vf, float* __restrict__ stats,
    const float* __restrict__ w1, const float* __restrict__ b1)
{
    __shared__ float w1s[112], b1s[16];
    __shared__ float ssum[16], ssq[16];
    int tid = threadIdx.x;
    for (int i = tid; i < 112; i += 256) w1s[i] = w1[i];
    if (tid < 16) { b1s[tid] = b1[tid]; ssum[tid] = 0.f; ssq[tid] = 0.f; }
    __syncthreads();

    float lsum[16], lsq[16];
#pragma unroll
    for (int u = 0; u < 16; ++u) { lsum[u] = 0.f; lsq[u] = 0.f; }

    for (int r = blockIdx.x * 256 + tid; r < NTR; r += gridDim.x * 256) {
        float v[FIN];
#pragma unroll
        for (int f = 0; f < FIN; ++f) v[f] = vf[(size_t)r * FIN + f];
#pragma unroll
        for (int u = 0; u < 16; ++u) {
            float h = b1s[u];
#pragma unroll
            for (int f = 0; f < FIN; ++f) h += v[f] * w1s[f * 16 + u];
            lsum[u] += h; lsq[u] += h * h;
        }
    }
#pragma unroll
    for (int u = 0; u < 16; ++u) {
        float a = lsum[u], b = lsq[u];
        for (int off = 32; off > 0; off >>= 1) {
            a += __shfl_down(a, off);
            b += __shfl_down(b, off);
        }
        if ((tid & 63) == 0) { atomicAdd(&ssum[u], a); atomicAdd(&ssq[u], b); }
    }
    __syncthreads();
    if (tid < 16) {
        atomicAdd(&stats[S_BN1 + tid], ssum[tid]);
        atomicAdd(&stats[S_BN1 + 16 + tid], ssq[tid]);
    }
}

// ------------------- finalize BN params -------------------
__global__ void k_finalize(float* __restrict__ stats, int base, int C, float invM,
                           const float* __restrict__ g, const float* __restrict__ be)
{
    int i = threadIdx.x;
    if (i < C) {
        float mean = stats[base + i] * invM;
        float var  = stats[base + C + i] * invM - mean * mean;
        float sc = g[i] * rsqrtf(var + BNEPS);
        stats[base + 2 * C + i] = sc;
        stats[base + 3 * C + i] = be[i] - mean * sc;
    }
}

// stage-1 (h1->bn1->relu, laf, mask, pwcf into LDS pc[TT*32])
__device__ __forceinline__ void stage1(
    int tid, int n, const float* __restrict__ vf,
    const float* w1s, const float* b1s, const float* sc1, const float* sh1,
    float* pwf, float* laf, float* mk, float* pc)
{
    {
        int u = tid & 15, tg = tid >> 4;
        for (int t = tg; t < TT; t += 16) {
            const float* vr = vf + (size_t)(n * TT + t) * FIN;
            float vv[FIN];
#pragma unroll
            for (int f = 0; f < FIN; ++f) vv[f] = vr[f];
            float h = b1s[u];
#pragma unroll
            for (int f = 0; f < FIN; ++f) h += vv[f] * w1s[f * 16 + u];
            pwf[t * 16 + u] = fmaxf(h * sc1[u] + sh1[u], 0.f);
            if (u == 0) {
                float mx = vv[0];
#pragma unroll
                for (int f = 1; f < FIN; ++f) mx = fmaxf(mx, vv[f]);
                mk[t] = (mx != 0.f) ? 1.f : 0.f;
            }
        }
    }
    __syncthreads();
    if (tid < 16) {   // laf = max over t, PRE-mask
        float m = pwf[tid];
        for (int t = 1; t < TT; ++t) m = fmaxf(m, pwf[t * 16 + tid]);
        laf[tid] = m;
    }
    __syncthreads();
    {
        int c = tid & 31, tg = tid >> 5;
        for (int t = tg; t < TT; t += 8)
            pc[t * 32 + c] = (c < 16 ? pwf[t * 16 + c] : laf[c - 16]) * mk[t];
    }
    __syncthreads();
}

// ---- k_pc: stage1 once; store pc (bf16) + mask; accumulate Gram G and colsum s ----
__global__ __launch_bounds__(256) void k_pc(
    const float* __restrict__ vf, const float* __restrict__ stats,
    __hip_bfloat16* __restrict__ pcg, float* __restrict__ mkg,
    float* __restrict__ Gg,
    const float* __restrict__ w1, const float* __restrict__ b1)
{
    __shared__ float w1s[112], b1s[16], sc1[16], sh1[16];
    __shared__ float pwf[TT * 16], laf[16], mk[TT];
    __shared__ __align__(16) float pc[TT * 32];
    int tid = threadIdx.x;
    for (int i = tid; i < 112; i += 256) w1s[i] = w1[i];
    if (tid < 16) {
        b1s[tid] = b1[tid];
        sc1[tid] = stats[S_BN1 + 32 + tid];
        sh1[tid] = stats[S_BN1 + 48 + tid];
    }
    __syncthreads();

    int gi = tid >> 3, gj = (tid & 7) * 4;
    float ga0 = 0.f, ga1 = 0.f, ga2 = 0.f, ga3 = 0.f;
    float sacc = 0.f;

    for (int n = blockIdx.x; n < NVOX; n += gridDim.x) {
        stage1(tid, n, vf, w1s, b1s, sc1, sh1, pwf, laf, mk, pc);
        // store pc bf16 + mask
        if (tid < 140) {
            int t = tid >> 2, part = tid & 3;
            short8 v;
#pragma unroll
            for (int j = 0; j < 8; ++j) v[j] = f2bfs(pc[t * 32 + part * 8 + j]);
            *(short8*)(pcg + ((size_t)n * TT + t) * 32 + part * 8) = v;
        }
        if (tid < TT) mkg[n * TT + tid] = mk[tid];
        // Gram accumulation: thread owns (gi, gj..gj+3)
        for (int t = 0; t < TT; ++t) {
            float xi = pc[t * 32 + gi];
            f32x4 xj = *(const f32x4*)&pc[t * 32 + gj];
            ga0 += xi * xj[0]; ga1 += xi * xj[1];
            ga2 += xi * xj[2]; ga3 += xi * xj[3];
        }
        if (tid < 32) {
            float a = 0.f;
            for (int t = 0; t < TT; ++t) a += pc[t * 32 + tid];
            sacc += a;
        }
        __syncthreads();   // protect mk/pc before next stage1 rewrite
    }
    atomicAdd(&Gg[gi * 32 + gj + 0], ga0);
    atomicAdd(&Gg[gi * 32 + gj + 1], ga1);
    atomicAdd(&Gg[gi * 32 + gj + 2], ga2);
    atomicAdd(&Gg[gi * 32 + gj + 3], ga3);
    if (tid < 32) atomicAdd(&Gg[1024 + tid], sacc);
}

// ---- BN2 scale/shift from Gram: sum h2 = s.w + N b ; sum h2^2 = w'Gw + 2b(s.w) + N b^2 ----
__global__ void k_bn2g(const float* __restrict__ Gg,
                       const float* __restrict__ w2, const float* __restrict__ b2,
                       const float* __restrict__ g2, const float* __restrict__ be2,
                       float* __restrict__ stats)
{
    int u = threadIdx.x;
    if (u >= 64) return;
    float wc[32];
#pragma unroll
    for (int c = 0; c < 32; ++c) wc[c] = w2[c * 64 + u];
    float dot = 0.f;
#pragma unroll
    for (int c = 0; c < 32; ++c) dot += Gg[1024 + c] * wc[c];
    float quad = 0.f;
    for (int c = 0; c < 32; ++c) {
        float a = 0.f;
#pragma unroll
        for (int c2 = 0; c2 < 32; ++c2) a += Gg[c * 32 + c2] * wc[c2];
        quad += wc[c] * a;
    }
    float b = b2[u];
    float N = (float)NTR;
    float mean = (dot + N * b) / N;
    float q = quad + 2.f * b * dot + N * b * b;
    float var = q / N - mean * mean;
    float sc = g2[u] * rsqrtf(var + BNEPS);
    stats[S_BN2 + 128 + u] = sc;
    stats[S_BN2 + 192 + u] = be2[u] - mean * sc;
}

// ---- MFMA VFE2+FCN: pc -> h2 -> pc2 -> h3 ; h3 max/min + BN3 sums ----
__global__ __launch_bounds__(256) void k_vfe3m(
    const __hip_bfloat16* __restrict__ pcg, const float* __restrict__ mkg,
    float* __restrict__ stats,
    float* __restrict__ h3max, float* __restrict__ h3min,
    const float* __restrict__ w2, const float* __restrict__ b2,
    const float* __restrict__ w3, const float* __restrict__ b3,
    const __hip_bfloat16* __restrict__ zp)
{
    __shared__ __align__(16) short pc2s[48 * 128];  // bf16, XOR-swizzled rows
    __shared__ float mkan[48];
    int tid = threadIdx.x;
    int l = tid & 63, w = tid >> 6;
    int lr = l & 15, lk = l >> 4;
    int cw2 = w * 16 + lr;

    short8 w2f;
#pragma unroll
    for (int j = 0; j < 8; ++j) w2f[j] = f2bfs(w2[(lk * 8 + j) * 64 + cw2]);
    int c3[2] = { (2 * w) * 16 + lr, (2 * w + 1) * 16 + lr };
    short8 w3f[2][4];
#pragma unroll
    for (int ni = 0; ni < 2; ++ni)
#pragma unroll
        for (int ks = 0; ks < 4; ++ks)
#pragma unroll
            for (int j = 0; j < 8; ++j)
                w3f[ni][ks][j] = f2bfs(w3[(ks * 32 + lk * 8 + j) * 128 + c3[ni]]);

    float sc2c = stats[S_BN2 + 128 + cw2], sh2c = stats[S_BN2 + 192 + cw2];
    float b2c = b2[cw2];
    float b3c[2] = { b3[c3[0]], b3[c3[1]] };
    float s3a[2] = { 0.f, 0.f }, q3a[2] = { 0.f, 0.f };

    if (tid < 48) mkan[tid] = 0.f;
    __syncthreads();

    char* pb = (char*)pc2s;
    for (int n = blockIdx.x; n < NVOX; n += gridDim.x) {
        if (tid < TT) mkan[tid] = mkg[n * TT + tid];
        f32x4 hacc[3];
#pragma unroll
        for (int mt = 0; mt < 3; ++mt) {
            int t = mt * 16 + lr;
            const short8* ap = (t < TT)
                ? (const short8*)(pcg + ((size_t)n * TT + t) * 32 + lk * 8)
                : (const short8*)zp;
            short8 a = *ap;
            hacc[mt] = { b2c, b2c, b2c, b2c };
            hacc[mt] = __builtin_amdgcn_mfma_f32_16x16x32_bf16(a, w2f, hacc[mt], 0, 0, 0);
        }
        float pw2[3][4];
#pragma unroll
        for (int mt = 0; mt < 3; ++mt)
#pragma unroll
            for (int r = 0; r < 4; ++r)
                pw2[mt][r] = fmaxf(hacc[mt][r] * sc2c + sh2c, 0.f);
        float lm = 0.f;
#pragma unroll
        for (int mt = 0; mt < 2; ++mt)
#pragma unroll
            for (int r = 0; r < 4; ++r) lm = fmaxf(lm, pw2[mt][r]);
        if (lk == 0) {
#pragma unroll
            for (int r = 0; r < 3; ++r) lm = fmaxf(lm, pw2[2][r]);
        }
        lm = fmaxf(lm, __shfl_xor(lm, 16));
        lm = fmaxf(lm, __shfl_xor(lm, 32));
        __syncthreads();
#pragma unroll
        for (int mt = 0; mt < 3; ++mt)
#pragma unroll
            for (int r = 0; r < 4; ++r) {
                int t = mt * 16 + lk * 4 + r;
                float mv = mkan[t];
                int swz = (t & 7) << 4;
                *(short*)(pb + t * 256 + ((2 * cw2) ^ swz)) = f2bfs(pw2[mt][r] * mv);
                *(short*)(pb + t * 256 + ((2 * (64 + cw2)) ^ swz)) = f2bfs(lm * mv);
            }
        __syncthreads();
        f32x4 acc3[2][3];
#pragma unroll
        for (int ni = 0; ni < 2; ++ni)
#pragma unroll
            for (int mt = 0; mt < 3; ++mt)
                acc3[ni][mt] = { b3c[ni], b3c[ni], b3c[ni], b3c[ni] };
#pragma unroll
        for (int mt = 0; mt < 3; ++mt) {
            int t = mt * 16 + lr;
            int swz = (t & 7) << 4;
            short8 a[4];
#pragma unroll
            for (int ks = 0; ks < 4; ++ks)
                a[ks] = *(const short8*)(pb + t * 256 + ((2 * (ks * 32 + lk * 8)) ^ swz));
#pragma unroll
            for (int ni = 0; ni < 2; ++ni)
#pragma unroll
                for (int ks = 0; ks < 4; ++ks)
                    acc3[ni][mt] = __builtin_amdgcn_mfma_f32_16x16x32_bf16(
                        a[ks], w3f[ni][ks], acc3[ni][mt], 0, 0, 0);
        }
#pragma unroll
        for (int ni = 0; ni < 2; ++ni) {
            float mx = -1e30f, mn = 1e30f, s = 0.f, q = 0.f;
#pragma unroll
            for (int mt = 0; mt < 3; ++mt)
#pragma unroll
                for (int r = 0; r < 4; ++r) {
                    int t = mt * 16 + lk * 4 + r;
                    if (t < TT) {
                        float h = acc3[ni][mt][r];
                        mx = fmaxf(mx, h); mn = fminf(mn, h);
                        s += h; q += h * h;
                    }
                }
            mx = fmaxf(mx, __shfl_xor(mx, 16)); mx = fmaxf(mx, __shfl_xor(mx, 32));
            mn = fminf(mn, __shfl_xor(mn, 16)); mn = fminf(mn, __shfl_xor(mn, 32));
            s += __shfl_xor(s, 16); s += __shfl_xor(s, 32);
            q += __shfl_xor(q, 16); q += __shfl_xor(q, 32);
            if (l < 16) {
                h3max[(size_t)n * 128 + c3[ni]] = mx;
                h3min[(size_t)n * 128 + c3[ni]] = mn;
                s3a[ni] += s; q3a[ni] += q;
            }
        }
    }
    if (l < 16) {
#pragma unroll
        for (int ni = 0; ni < 2; ++ni) {
            atomicAdd(&stats[S_BN3 + c3[ni]], s3a[ni]);
            atomicAdd(&stats[S_BN3 + 128 + c3[ni]], q3a[ni]);
        }
    }
}

// ------------------- owner resolution (last index wins) -------------------
__global__ void k_owner(const int* __restrict__ coords, int* __restrict__ owner)
{
    int n = blockIdx.x * 256 + threadIdx.x;
    if (n >= NVOX) return;
    int cx = coords[n * 4 + 1], cy = coords[n * 4 + 2], cz = coords[n * 4 + 3];
    atomicMax(&owner[(cx * GYD + cy) * GZD + cz], n);
}

// ---------- bn3+relu via max/min, scatter into dense [NPOS][128] bf16 ----------
__global__ __launch_bounds__(128) void k_scatter(
    const float* __restrict__ h3max, const float* __restrict__ h3min,
    const int* __restrict__ coords, const int* __restrict__ owner,
    const float* __restrict__ stats, __hip_bfloat16* __restrict__ dense)
{
    int n = blockIdx.x, k = threadIdx.x;
    int cx = coords[n * 4 + 1], cy = coords[n * 4 + 2], cz = coords[n * 4 + 3];
    int cell = (cx * GYD + cy) * GZD + cz;
    if (owner[cell] != n) return;
    float sc = stats[S_BN3 + 256 + k], sh = stats[S_BN3 + 384 + k];
    float h = (sc >= 0.f) ? h3max[(size_t)n * 128 + k] : h3min[(size_t)n * 128 + k];
    dense[(size_t)cell * 128 + k] = f2bf(fmaxf(h * sc + sh, 0.f));
}

// ---------- weight relayout: src [OC=64][IC][27] f32 -> dst [27][kk=IC/8][oc][8] bf16 ----------
// element (d, kk, oc, j) = src channel ch = (kk>>2)*32 + (kk&3)*8 + j of oc, tap d
__global__ void k_wcvt2(const float* __restrict__ src, __hip_bfloat16* __restrict__ dst,
                        int IC)
{
    int i = blockIdx.x * 256 + threadIdx.x;
    int total = 27 * 64 * IC;
    if (i >= total) return;
    int perd = 64 * IC;
    int d = i / perd, rem = i % perd;
    int kk = rem / 512;          // (k*4 + lk)
    int rem2 = rem % 512;
    int oc = rem2 >> 3, j = rem2 & 7;
    int ch = (kk >> 2) * 32 + (kk & 3) * 8 + j;
    dst[i] = f2bf(src[((size_t)oc * IC + ch) * 27 + d]);
}

// ---------- MFMA implicit-GEMM 3x3x3 conv, LDS-staged A + coalesced B ----------
// WG = 256 thr = 4 waves; tile 64 pos x 64 oc; wave = 32 pos x 32 oc (2x2 mfma tiles).
// A halo staged per (dx,dy) group: 68 contiguous rows + zero row 68, XOR-swizzled.
template <int IC>
__global__ __launch_bounds__(256) void k_convm(
    const __hip_bfloat16* __restrict__ in, const __hip_bfloat16* __restrict__ wbn,
    const float* __restrict__ bias, __hip_bfloat16* __restrict__ outp,
    float* __restrict__ sumAcc, float* __restrict__ sqAcc)
{
    constexpr int KS = IC / 32;          // k-steps per tap
    constexpr int ROWB = IC * 2;         // bytes per row
    constexpr int CPR = ROWB / 16;       // 16B chunks per row
    __shared__ __align__(16) char atile[69 * ROWB];
    __shared__ float ssum[64], ssq[64];
    int tid = threadIdx.x;
    if (tid < 64) { ssum[tid] = 0.f; ssq[tid] = 0.f; }
    if (tid < CPR) *(int4v*)(atile + 68 * ROWB + tid * 16) = int4v{0, 0, 0, 0};

    int l = tid & 63, wave = tid >> 6;
    int wm = wave >> 1, wn = wave & 1;
    int lr = l & 15, lk = l >> 4;

    int pbase = blockIdx.x * 64;
    int p0 = pbase + wm * 32 + lr;       // mt=0 position
    int p1 = p0 + 16;                    // mt=1
    int z0 = p0 % 10, y0 = (p0 / 10) % 128, x0 = p0 / 1280;
    int z1 = p1 % 10, y1c = (p1 / 10) % 128, x1 = p1 / 1280;

    int oc0 = wn * 32 + lr, oc1 = oc0 + 16;
    const short8* wb8 = (const short8*)wbn;

    float bb0 = bias[oc0], bb1 = bias[oc1];
    f32x4 acc[2][2];
#pragma unroll
    for (int t = 0; t < 2; ++t) {
        acc[t][0] = { bb0, bb0, bb0, bb0 };
        acc[t][1] = { bb1, bb1, bb1, bb1 };
    }

    for (int g = 0; g < 9; ++g) {
        int dx = g / 3 - 1, dy = g % 3 - 1;
        int offg = (dx * 128 + dy) * 10;
        __syncthreads();                 // prior group's reads done
        // stage rows pbase+offg-1 .. +66 (68 rows), coalesced, swizzled
        for (int c = tid; c < 68 * CPR; c += 256) {
            int r = c / CPR, sub = c - r * CPR;
            int grow = pbase + offg - 1 + r;
            grow = grow < 0 ? 0 : (grow > NPOS - 1 ? NPOS - 1 : grow);
            int4v v = *(const int4v*)(in + (size_t)grow * IC + sub * 8);
            *(int4v*)(atile + r * ROWB + ((sub * 16) ^ ((r & 7) << 4))) = v;
        }
        __syncthreads();                 // stage ready
        bool vxy0 = ((unsigned)(x0 + dx) < 128u) & ((unsigned)(y0 + dy) < 128u);
        bool vxy1 = ((unsigned)(x1 + dx) < 128u) & ((unsigned)(y1c + dy) < 128u);
#pragma unroll
        for (int dzi = 0; dzi < 3; ++dzi) {
            int dz = dzi - 1;
            int d = g * 3 + dzi;
            bool v0 = vxy0 & ((unsigned)(z0 + dz) < 10u);
            bool v1 = vxy1 & ((unsigned)(z1 + dz) < 10u);
            int ra0 = v0 ? (wm * 32 + lr + dz + 1) : 68;
            int ra1 = v1 ? (wm * 32 + 16 + lr + dz + 1) : 68;
            short8 a0[KS], a1[KS], b0[KS], b1[KS];
#pragma unroll
            for (int k = 0; k < KS; ++k) {
                size_t bi = ((size_t)(d * KS + k) * 4 + lk) * 64;
                b0[k] = wb8[bi + oc0];
                b1[k] = wb8[bi + oc1];
                int xb = lk * 16 + k * 64;
                a0[k] = *(const short8*)(atile + ra0 * ROWB + (xb ^ ((ra0 & 7) << 4)));
                a1[k] = *(const short8*)(atile + ra1 * ROWB + (xb ^ ((ra1 & 7) << 4)));
            }
#pragma unroll
            for (int k = 0; k < KS; ++k) {
                acc[0][0] = __builtin_amdgcn_mfma_f32_16x16x32_bf16(a0[k], b0[k], acc[0][0], 0, 0, 0);
                acc[0][1] = __builtin_amdgcn_mfma_f32_16x16x32_bf16(a0[k], b1[k], acc[0][1], 0, 0, 0);
                acc[1][0] = __builtin_amdgcn_mfma_f32_16x16x32_bf16(a1[k], b0[k], acc[1][0], 0, 0, 0);
                acc[1][1] = __builtin_amdgcn_mfma_f32_16x16x32_bf16(a1[k], b1[k], acc[1][1], 0, 0, 0);
            }
        }
    }

    // store: D row (position) = (lane>>4)*4 + reg, D col (oc) = lane&15
    float s0 = 0.f, q0 = 0.f, s1 = 0.f, q1 = 0.f;
#pragma unroll
    for (int t = 0; t < 2; ++t) {
#pragma unroll
        for (int r = 0; r < 4; ++r) {
            int prow = pbase + wm * 32 + t * 16 + lk * 4 + r;
            float v0c = acc[t][0][r], v1c = acc[t][1][r];
            outp[(size_t)prow * 64 + oc0] = f2bf(v0c);
            outp[(size_t)prow * 64 + oc1] = f2bf(v1c);
            s0 += v0c; q0 += v0c * v0c;
            s1 += v1c; q1 += v1c * v1c;
        }
    }
    s0 += __shfl_xor(s0, 16); s0 += __shfl_xor(s0, 32);
    q0 += __shfl_xor(q0, 16); q0 += __shfl_xor(q0, 32);
    s1 += __shfl_xor(s1, 16); s1 += __shfl_xor(s1, 32);
    q1 += __shfl_xor(q1, 16); q1 += __shfl_xor(q1, 32);
    if (l < 16) {
        atomicAdd(&ssum[oc0], s0); atomicAdd(&ssq[oc0], q0);
        atomicAdd(&ssum[oc1], s1); atomicAdd(&ssq[oc1], q1);
    }
    __syncthreads();
    if (tid < 64) {
        atomicAdd(&sumAcc[tid], ssum[tid]);
        atomicAdd(&sqAcc[tid], ssq[tid]);
    }
}

// ---------- conv3: in [NPOS][64] -> y3 [NPOS][2] ----------
__global__ __launch_bounds__(256) void k_conv3(
    const __hip_bfloat16* __restrict__ in, const float* __restrict__ w,
    const float* __restrict__ bias, float* __restrict__ y3,
    float* __restrict__ sumAcc, float* __restrict__ sqAcc)
{
    __shared__ float wred[8];
    int tid = threadIdx.x;
    int p = blockIdx.x * 256 + tid;
    int z = p % 10, y = (p / 10) % 128, x = p / 1280;
    float a0 = bias[0], a1 = bias[1];
    for (int d = 0; d < 27; ++d) {
        int dx = d / 9 - 1, dy = (d / 3) % 3 - 1, dz = d % 3 - 1;
        if (!(((unsigned)(x + dx) < 128u) & ((unsigned)(y + dy) < 128u) & ((unsigned)(z + dz) < 10u)))
            continue;
        int off = (dx * 128 + dy) * 10 + dz;
        const short8* ip = (const short8*)(in + (size_t)(p + off) * 64);
#pragma unroll
        for (int cb = 0; cb < 8; ++cb) {
            short8 v = ip[cb];
#pragma unroll
            for (int j = 0; j < 8; ++j) {
                int ic = cb * 8 + j;
                float f = bfs2f(v[j]);
                a0 += f * w[(ic) * 27 + d];
                a1 += f * w[(64 + ic) * 27 + d];
            }
        }
    }
    y3[(size_t)p * 2 + 0] = a0;
    y3[(size_t)p * 2 + 1] = a1;

    float s0 = a0, q0 = a0 * a0, s1 = a1, q1 = a1 * a1;
    for (int o = 32; o > 0; o >>= 1) {
        s0 += __shfl_down(s0, o); q0 += __shfl_down(q0, o);
        s1 += __shfl_down(s1, o); q1 += __shfl_down(q1, o);
    }
    int wv = tid >> 6;
    if ((tid & 63) == 0) { wred[wv] = s0; wred[4 + wv] = q0; }
    __syncthreads();
    if ((tid & 63) == 0 && wv == 0) {
        atomicAdd(&sumAcc[0], wred[0] + wred[1] + wred[2] + wred[3]);
        atomicAdd(&sqAcc[0], wred[4] + wred[5] + wred[6] + wred[7]);
    }
    __syncthreads();
    if ((tid & 63) == 0) { wred[wv] = s1; wred[4 + wv] = q1; }
    __syncthreads();
    if ((tid & 63) == 0 && wv == 0) {
        atomicAdd(&sumAcc[1], wred[0] + wred[1] + wred[2] + wred[3]);
        atomicAdd(&sqAcc[1], wred[4] + wred[5] + wred[6] + wred[7]);
    }
}

// ---------- vectorized bn+relu in place, layout [NPOS][64] ----------
__global__ void k_bnrelu_v(__hip_bfloat16* __restrict__ ybuf,
                           const float* __restrict__ stats, int base)
{
    const int C = 64;
    int nvec = NPOS * C / 8;
    short8* yv = (short8*)ybuf;
    for (int i = blockIdx.x * 256 + threadIdx.x; i < nvec; i += gridDim.x * 256) {
        int cb = (i & 7) * 8;
        short8 v = yv[i];
        short8 r;
#pragma unroll
        for (int j = 0; j < 8; ++j) {
            float f = bfs2f(v[j]) * stats[base + 2 * C + cb + j] + stats[base + 3 * C + cb + j];
            r[j] = f2bfs(fmaxf(f, 0.f));
        }
        yv[i] = r;
    }
}

// ------------------- gather + bn + relu + softmax -------------------
__global__ void k_out(const float* __restrict__ y3, const int* __restrict__ coords,
                      const float* __restrict__ stats, float* __restrict__ out)
{
    int n = blockIdx.x * 256 + threadIdx.x;
    if (n >= NVOX) return;
    int cx = coords[n * 4 + 1], cy = coords[n * 4 + 2], cz = coords[n * 4 + 3];
    int cell = (cx * GYD + cy) * GZD + cz;
    float a = fmaxf(y3[(size_t)cell * 2 + 0] * stats[S_C3 + 4] + stats[S_C3 + 6], 0.f);
    float b = fmaxf(y3[(size_t)cell * 2 + 1] * stats[S_C3 + 5] + stats[S_C3 + 7], 0.f);
    float m = fmaxf(a, b);
    float e0 = expf(a - m), e1 = expf(b - m);
    float inv = 1.f / (e0 + e1);
    out[n * 2 + 0] = e0 * inv;
    out[n * 2 + 1] = e1 * inv;
}

extern "C" void kernel_launch(void* const* d_in, const int* in_sizes, int n_in,
                              void* d_out, int out_size, void* d_ws, size_t ws_size,
                              hipStream_t stream)
{
    const float* vf     = (const float*)d_in[0];
    const int*   coords = (const int*)d_in[1];
    const float* w1  = (const float*)d_in[2];
    const float* b1  = (const float*)d_in[3];
    const float* g1  = (const float*)d_in[4];
    const float* be1 = (const float*)d_in[5];
    const float* w2  = (const float*)d_in[6];
    const float* b2  = (const float*)d_in[7];
    const float* g2  = (const float*)d_in[8];
    const float* be2 = (const float*)d_in[9];
    const float* w3  = (const float*)d_in[10];
    const float* b3  = (const float*)d_in[11];
    const float* g3  = (const float*)d_in[12];
    const float* be3 = (const float*)d_in[13];
    const float* c1w = (const float*)d_in[14];
    const float* c1b = (const float*)d_in[15];
    const float* c1g = (const float*)d_in[16];
    const float* c1be= (const float*)d_in[17];
    const float* c2w = (const float*)d_in[18];
    const float* c2b = (const float*)d_in[19];
    const float* c2g = (const float*)d_in[20];
    const float* c2be= (const float*)d_in[21];
    const float* c3w = (const float*)d_in[22];
    const float* c3b = (const float*)d_in[23];
    const float* c3g = (const float*)d_in[24];
    const float* c3be= (const float*)d_in[25];

    if (ws_size < WS_BYTES) return;

    char* base = (char*)d_ws;
    float* stats = (float*)(base + O_STATS);
    __hip_bfloat16* zp = (__hip_bfloat16*)(base + O_ZERO);
    int*   owner = (int*)(base + O_OWNER);
    float* Gg    = (float*)(base + O_G);
    float* h3max = (float*)(base + O_H3MAX);
    float* h3min = (float*)(base + O_H3MIN);
    __hip_bfloat16* wb1 = (__hip_bfloat16*)(base + O_WB1);
    __hip_bfloat16* wb2 = (__hip_bfloat16*)(base + O_WB2);
    __hip_bfloat16* pcg = (__hip_bfloat16*)(base + O_PC);
    float* mkg          = (float*)(base + O_MKF);
    __hip_bfloat16* dense = (__hip_bfloat16*)(base + O_DENSE);
    __hip_bfloat16* y1    = (__hip_bfloat16*)(base + O_Y1);
    __hip_bfloat16* y2    = (__hip_bfloat16*)(base + O_Y2);
    float* y3             = (float*)(base + O_Y3);

    hipMemsetAsync(stats, 0, STATS_FLOATS * sizeof(float), stream);
    hipMemsetAsync((void*)zp, 0, 256, stream);
    hipMemsetAsync(owner, 0xFF, (size_t)NPOS * sizeof(int), stream);
    hipMemsetAsync(Gg, 0, 1056 * sizeof(float), stream);

    k_stats1<<<1024, 256, 0, stream>>>(vf, stats, w1, b1);
    k_finalize<<<1, 128, 0, stream>>>(stats, S_BN1, 16, 1.f / NTR, g1, be1);
    k_pc<<<2048, 256, 0, stream>>>(vf, stats, pcg, mkg, Gg, w1, b1);
    k_bn2g<<<1, 64, 0, stream>>>(Gg, w2, b2, g2, be2, stats);
    k_vfe3m<<<1024, 256, 0, stream>>>(pcg, mkg, stats, h3max, h3min,
                                      w2, b2, w3, b3, zp);
    k_finalize<<<1, 128, 0, stream>>>(stats, S_BN3, 128, 1.f / NTR, g3, be3);
    k_owner<<<(NVOX + 255) / 256, 256, 0, stream>>>(coords, owner);
    hipMemsetAsync((void*)dense, 0, (size_t)NPOS * 128 * sizeof(__hip_bfloat16), stream);
    k_scatter<<<NVOX, 128, 0, stream>>>(h3max, h3min, coords, owner, stats, dense);

    k_wcvt2<<<(64 * 128 * 27 + 255) / 256, 256, 0, stream>>>(c1w, wb1, 128);
    k_wcvt2<<<(64 * 64 * 27 + 255) / 256, 256, 0, stream>>>(c2w, wb2, 64);

    k_convm<128><<<NPOS / 64, 256, 0, stream>>>(dense, wb1, c1b, y1,
                                                &stats[S_C1], &stats[S_C1 + 64]);
    k_finalize<<<1, 128, 0, stream>>>(stats, S_C1, 64, 1.f / NPOS, c1g, c1be);
    k_bnrelu_v<<<1024, 256, 0, stream>>>(y1, stats, S_C1);

    k_convm<64><<<NPOS / 64, 256, 0, stream>>>(y1, wb2, c2b, y2,
                                               &stats[S_C2], &stats[S_C2 + 64]);
    k_finalize<<<1, 128, 0, stream>>>(stats, S_C2, 64, 1.f / NPOS, c2g, c2be);
    k_bnrelu_v<<<1024, 256, 0, stream>>>(y2, stats, S_C2);

    k_conv3<<<NPOS / 256, 256, 0, stream>>>(y2, c3w, c3b, y3,
                                            &stats[S_C3], &stats[S_C3 + 2]);
    k_finalize<<<1, 128, 0, stream>>>(stats, S_C3, 2, 1.f / NPOS, c3g, c3be);

    k_out<<<(NVOX + 255) / 256, 256, 0, stream>>>(y3, coords, stats, (float*)d_out);
}

// Round 13
// 804.296 us; speedup vs baseline: 3.0737x; 1.0743x over previous
//
#include <hip/hip_runtime.h>
#include <hip/hip_bf16.h>
#include <cstddef>
#include <cstdint>

#define TT 35
#define NVOX 20000
#define NTR 700000
#define FIN 7
#define GXD 128
#define GYD 128
#define GZD 10
#define NPOS 163840
#define BNEPS 1e-5f
#define VB 8                      // voxels per k_pc block (20000 = 2500*8)

// stats layout (float offsets): per group {sum[C], sq[C], scale[C], shift[C]}
#define S_BN1 0
#define S_BN2 64
#define S_BN3 320
#define S_C1  832
#define S_C2  1088
#define S_C3  1344
#define STATS_FLOATS 2048

// byte offsets inside ws (unchanged total: 84,062,208 B)
#define O_STATS 0ull
#define O_ZERO  8192ull           // 256 B zero page
#define O_OWNER 12288ull          // 163840*4
#define O_H3MAX 667648ull         // 20000*128*4
#define O_G     O_H3MAX           // 1152 f32: G32 (1024) + s32 (32) + G7/s7 (56) @1088
#define O_H3MIN 10907648ull       // 20000*128*4
#define O_WB1   667648ull         // bf16 27*64*128 (after scatter, h3max dead)
#define O_WB2   1110016ull        // bf16 27*64*64
#define O_DENSE 21147648ull       // bf16 [NPOS][128]
#define O_PC    O_DENSE           // bf16 [NTR][32] (dead before dense memset)
#define O_MKF   67284992ull       // f32 [NTR] mask (dead before conv1 writes y1)
#define O_Y1    63090688ull       // bf16 [NPOS][64]
#define O_Y2    O_DENSE           // bf16 [NPOS][64]
#define O_Y3    O_H3MIN           // f32 [NPOS][2]
#define WS_BYTES 84062208ull

typedef __attribute__((ext_vector_type(8))) short short8;
typedef __attribute__((ext_vector_type(4))) float f32x4;
typedef __attribute__((ext_vector_type(4))) int int4v;

__device__ __forceinline__ float bf2f(__hip_bfloat16 x) { return __bfloat162float(x); }
__device__ __forceinline__ __hip_bfloat16 f2bf(float x) { return __float2bfloat16(x); }
__device__ __forceinline__ float bfs2f(short s) {
    union { unsigned u; float f; } cv; cv.u = ((unsigned)(unsigned short)s) << 16; return cv.f;
}
__device__ __forceinline__ short f2bfs(float f) {
    __hip_bfloat16 h = __float2bfloat16(f);
    return *(short*)&h;
}

// ---- k_gram7: G7 (7x7 upper triangle, 28) + colsum (7) of vf over 700k rows ----
__global__ __launch_bounds__(256) void k_gram7(
    const float* __restrict__ vf, float* __restrict__ G7)
{
    __shared__ __align__(16) float vs[256 * 7];
    __shared__ float ss[35];
    int tid = threadIdx.x;
    if (tid < 35) ss[tid] = 0.f;

    float acc[35];
#pragma unroll
    for (int a = 0; a < 35; ++a) acc[a] = 0.f;

    for (int base = blockIdx.x * 256; base < NTR; base += gridDim.x * 256) {
        int nrows = NTR - base; if (nrows > 256) nrows = 256;
        __syncthreads();
        for (int i = tid; i < nrows * 7; i += 256) vs[i] = vf[(size_t)base * 7 + i];
        __syncthreads();
        if (tid < nrows) {
            float v[7];
#pragma unroll
            for (int f = 0; f < 7; ++f) v[f] = vs[tid * 7 + f];
            int k = 0;
#pragma unroll
            for (int i = 0; i < 7; ++i) {
                acc[28 + i] += v[i];
#pragma unroll
                for (int j = i; j < 7; ++j) acc[k++] += v[i] * v[j];
            }
        }
    }
    __syncthreads();
#pragma unroll
    for (int a = 0; a < 35; ++a) {
        float r = acc[a];
        for (int o = 32; o > 0; o >>= 1) r += __shfl_down(r, o);
        if ((tid & 63) == 0) atomicAdd(&ss[a], r);
    }
    __syncthreads();
    if (tid < 35) atomicAdd(&G7[tid], ss[tid]);
}

// ---- k_bn1g: BN1 scale/shift from G7 ----
__global__ void k_bn1g(const float* __restrict__ G7,
                       const float* __restrict__ w1, const float* __restrict__ b1,
                       const float* __restrict__ g1, const float* __restrict__ be1,
                       float* __restrict__ stats)
{
    int u = threadIdx.x;
    if (u >= 16) return;
    float w[7];
#pragma unroll
    for (int f = 0; f < 7; ++f) w[f] = w1[f * 16 + u];
    float dot = 0.f;
#pragma unroll
    for (int f = 0; f < 7; ++f) dot += G7[28 + f] * w[f];
    float quad = 0.f;
    int k = 0;
#pragma unroll
    for (int i = 0; i < 7; ++i)
#pragma unroll
        for (int j = i; j < 7; ++j) {
            float gij = G7[k++];
            quad += (i == j ? 1.f : 2.f) * w[i] * w[j] * gij;
        }
    float b = b1[u];
    float N = (float)NTR;
    float mean = (dot + N * b) / N;
    float q = quad + 2.f * b * dot + N * b * b;
    float var = q / N - mean * mean;
    float sc = g1[u] * rsqrtf(var + BNEPS);
    stats[S_BN1 + 32 + u] = sc;
    stats[S_BN1 + 48 + u] = be1[u] - mean * sc;
}

// ------------------- finalize BN params -------------------
__global__ void k_finalize(float* __restrict__ stats, int base, int C, float invM,
                           const float* __restrict__ g, const float* __restrict__ be)
{
    int i = threadIdx.x;
    if (i < C) {
        float mean = stats[base + i] * invM;
        float var  = stats[base + C + i] * invM - mean * mean;
        float sc = g[i] * rsqrtf(var + BNEPS);
        stats[base + 2 * C + i] = sc;
        stats[base + 3 * C + i] = be[i] - mean * sc;
    }
}

// ---- k_pc: batched 8 voxels/block; stage1 + pcg/mkg store + Gram decomposition ----
__global__ __launch_bounds__(256) void k_pc(
    const float* __restrict__ vf, const float* __restrict__ stats,
    __hip_bfloat16* __restrict__ pcg, float* __restrict__ mkg,
    float* __restrict__ Gg,
    const float* __restrict__ w1, const float* __restrict__ b1)
{
    __shared__ float w1s[112], b1s[16], sc1[16], sh1[16];
    __shared__ float vfs[VB * 35 * 7];        // 1960 f
    __shared__ float pwfs[VB * 35 * 17];      // padded rows (17)
    __shared__ float lafs[VB][16], s16[VB][16], cnt[VB];
    __shared__ float mks[VB * 35];
    int tid = threadIdx.x;
    for (int i = tid; i < 112; i += 256) w1s[i] = w1[i];
    if (tid < 16) {
        b1s[tid] = b1[tid];
        sc1[tid] = stats[S_BN1 + 32 + tid];
        sh1[tid] = stats[S_BN1 + 48 + tid];
    }
    int n0 = blockIdx.x * VB;

    // phase 0: stage vf (coalesced)
    for (int i = tid; i < VB * 245; i += 256) vfs[i] = vf[(size_t)n0 * 245 + i];
    __syncthreads();

    // phase 1: h1 -> bn1 -> relu -> pwf ; mask
    for (int i = tid; i < VB * 560; i += 256) {
        int v = i / 560, rem = i - v * 560;
        int t = rem >> 4, u = rem & 15;
        const float* vr = &vfs[(v * 35 + t) * 7];
        float h = b1s[u];
#pragma unroll
        for (int f = 0; f < 7; ++f) h += vr[f] * w1s[f * 16 + u];
        pwfs[(v * 35 + t) * 17 + u] = fmaxf(h * sc1[u] + sh1[u], 0.f);
        if (u == 0) {
            float mx = vr[0];
#pragma unroll
            for (int f = 1; f < 7; ++f) mx = fmaxf(mx, vr[f]);
            mks[v * 35 + t] = (mx != 0.f) ? 1.f : 0.f;
        }
    }
    __syncthreads();

    // phase 2: laf (pre-mask), s16 = sum_t mk*pwf, cnt = sum_t mk
    if (tid < VB * 16) {
        int v = tid >> 4, u = tid & 15;
        float m = 0.f, s = 0.f, c = 0.f;
        for (int t = 0; t < 35; ++t) {
            float p = pwfs[(v * 35 + t) * 17 + u];
            float mk = mks[v * 35 + t];
            m = fmaxf(m, p);
            s += p * mk;
            if (u == 0) c += mk;
        }
        lafs[v][u] = m;
        s16[v][u] = s;
        if (u == 0) cnt[v] = c;
    }
    __syncthreads();

    // phase 3a: store pcg (bf16 short8 chunks) + mkg
    for (int c = tid; c < VB * 140; c += 256) {
        int v = c / 140, rem = c - v * 140;
        int t = rem >> 2, p = rem & 3;
        float mk = mks[v * 35 + t];
        short8 o;
        if (p < 2) {
#pragma unroll
            for (int j = 0; j < 8; ++j)
                o[j] = f2bfs(pwfs[(v * 35 + t) * 17 + p * 8 + j] * mk);
        } else {
#pragma unroll
            for (int j = 0; j < 8; ++j)
                o[j] = f2bfs(lafs[v][(p - 2) * 8 + j] * mk);
        }
        *(short8*)(pcg + ((size_t)(n0 + v) * 35 + t) * 32 + p * 8) = o;
    }
    for (int i = tid; i < VB * 35; i += 256) mkg[(size_t)n0 * 35 + i] = mks[i];

    // phase 3b: Gram top-left 16x16 (the only long loop)
    {
        int i = tid >> 4, j = tid & 15;
        float g = 0.f;
        for (int r = 0; r < VB * 35; ++r)
            g += mks[r] * pwfs[r * 17 + i] * pwfs[r * 17 + j];
        atomicAdd(&Gg[i * 32 + j], g);

        // phase 3c: laf-involved blocks via rank-1 per-voxel terms
        float tr = 0.f, br = 0.f;
#pragma unroll
        for (int v = 0; v < VB; ++v) {
            tr += s16[v][i] * lafs[v][j];
            br += cnt[v] * lafs[v][i] * lafs[v][j];
        }
        atomicAdd(&Gg[i * 32 + 16 + j], tr);
        atomicAdd(&Gg[(16 + j) * 32 + i], tr);
        atomicAdd(&Gg[(16 + i) * 32 + 16 + j], br);
    }
    if (tid < 16) {
        float s = 0.f;
#pragma unroll
        for (int v = 0; v < VB; ++v) s += s16[v][tid];
        atomicAdd(&Gg[1024 + tid], s);
    } else if (tid < 32) {
        int b = tid - 16;
        float s = 0.f;
#pragma unroll
        for (int v = 0; v < VB; ++v) s += cnt[v] * lafs[v][b];
        atomicAdd(&Gg[1024 + tid], s);
    }
}

// ---- BN2 scale/shift from Gram: sum h2 = s.w + N b ; sum h2^2 = w'Gw + 2b(s.w) + N b^2 ----
__global__ void k_bn2g(const float* __restrict__ Gg,
                       const float* __restrict__ w2, const float* __restrict__ b2,
                       const float* __restrict__ g2, const float* __restrict__ be2,
                       float* __restrict__ stats)
{
    int u = threadIdx.x;
    if (u >= 64) return;
    float wc[32];
#pragma unroll
    for (int c = 0; c < 32; ++c) wc[c] = w2[c * 64 + u];
    float dot = 0.f;
#pragma unroll
    for (int c = 0; c < 32; ++c) dot += Gg[1024 + c] * wc[c];
    float quad = 0.f;
    for (int c = 0; c < 32; ++c) {
        float a = 0.f;
#pragma unroll
        for (int c2 = 0; c2 < 32; ++c2) a += Gg[c * 32 + c2] * wc[c2];
        quad += wc[c] * a;
    }
    float b = b2[u];
    float N = (float)NTR;
    float mean = (dot + N * b) / N;
    float q = quad + 2.f * b * dot + N * b * b;
    float var = q / N - mean * mean;
    float sc = g2[u] * rsqrtf(var + BNEPS);
    stats[S_BN2 + 128 + u] = sc;
    stats[S_BN2 + 192 + u] = be2[u] - mean * sc;
}

// ---- MFMA VFE2+FCN: pc -> h2 -> pc2 -> h3 ; h3 max/min + BN3 sums ----
__global__ __launch_bounds__(256) void k_vfe3m(
    const __hip_bfloat16* __restrict__ pcg, const float* __restrict__ mkg,
    float* __restrict__ stats,
    float* __restrict__ h3max, float* __restrict__ h3min,
    const float* __restrict__ w2, const float* __restrict__ b2,
    const float* __restrict__ w3, const float* __restrict__ b3,
    const __hip_bfloat16* __restrict__ zp)
{
    __shared__ __align__(16) short pc2s[48 * 128];  // bf16, XOR-swizzled rows
    __shared__ float mkan[48];
    int tid = threadIdx.x;
    int l = tid & 63, w = tid >> 6;
    int lr = l & 15, lk = l >> 4;
    int cw2 = w * 16 + lr;

    short8 w2f;
#pragma unroll
    for (int j = 0; j < 8; ++j) w2f[j] = f2bfs(w2[(lk * 8 + j) * 64 + cw2]);
    int c3[2] = { (2 * w) * 16 + lr, (2 * w + 1) * 16 + lr };
    short8 w3f[2][4];
#pragma unroll
    for (int ni = 0; ni < 2; ++ni)
#pragma unroll
        for (int ks = 0; ks < 4; ++ks)
#pragma unroll
            for (int j = 0; j < 8; ++j)
                w3f[ni][ks][j] = f2bfs(w3[(ks * 32 + lk * 8 + j) * 128 + c3[ni]]);

    float sc2c = stats[S_BN2 + 128 + cw2], sh2c = stats[S_BN2 + 192 + cw2];
    float b2c = b2[cw2];
    float b3c[2] = { b3[c3[0]], b3[c3[1]] };
    float s3a[2] = { 0.f, 0.f }, q3a[2] = { 0.f, 0.f };

    if (tid < 48) mkan[tid] = 0.f;
    __syncthreads();

    char* pb = (char*)pc2s;
    for (int n = blockIdx.x; n < NVOX; n += gridDim.x) {
        if (tid < TT) mkan[tid] = mkg[n * TT + tid];
        f32x4 hacc[3];
#pragma unroll
        for (int mt = 0; mt < 3; ++mt) {
            int t = mt * 16 + lr;
            const short8* ap = (t < TT)
                ? (const short8*)(pcg + ((size_t)n * TT + t) * 32 + lk * 8)
                : (const short8*)zp;
            short8 a = *ap;
            hacc[mt] = { b2c, b2c, b2c, b2c };
            hacc[mt] = __builtin_amdgcn_mfma_f32_16x16x32_bf16(a, w2f, hacc[mt], 0, 0, 0);
        }
        float pw2[3][4];
#pragma unroll
        for (int mt = 0; mt < 3; ++mt)
#pragma unroll
            for (int r = 0; r < 4; ++r)
                pw2[mt][r] = fmaxf(hacc[mt][r] * sc2c + sh2c, 0.f);
        float lm = 0.f;
#pragma unroll
        for (int mt = 0; mt < 2; ++mt)
#pragma unroll
            for (int r = 0; r < 4; ++r) lm = fmaxf(lm, pw2[mt][r]);
        if (lk == 0) {
#pragma unroll
            for (int r = 0; r < 3; ++r) lm = fmaxf(lm, pw2[2][r]);
        }
        lm = fmaxf(lm, __shfl_xor(lm, 16));
        lm = fmaxf(lm, __shfl_xor(lm, 32));
        __syncthreads();
#pragma unroll
        for (int mt = 0; mt < 3; ++mt)
#pragma unroll
            for (int r = 0; r < 4; ++r) {
                int t = mt * 16 + lk * 4 + r;
                float mv = mkan[t];
                int swz = (t & 7) << 4;
                *(short*)(pb + t * 256 + ((2 * cw2) ^ swz)) = f2bfs(pw2[mt][r] * mv);
                *(short*)(pb + t * 256 + ((2 * (64 + cw2)) ^ swz)) = f2bfs(lm * mv);
            }
        __syncthreads();
        f32x4 acc3[2][3];
#pragma unroll
        for (int ni = 0; ni < 2; ++ni)
#pragma unroll
            for (int mt = 0; mt < 3; ++mt)
                acc3[ni][mt] = { b3c[ni], b3c[ni], b3c[ni], b3c[ni] };
#pragma unroll
        for (int mt = 0; mt < 3; ++mt) {
            int t = mt * 16 + lr;
            int swz = (t & 7) << 4;
            short8 a[4];
#pragma unroll
            for (int ks = 0; ks < 4; ++ks)
                a[ks] = *(const short8*)(pb + t * 256 + ((2 * (ks * 32 + lk * 8)) ^ swz));
#pragma unroll
            for (int ni = 0; ni < 2; ++ni)
#pragma unroll
                for (int ks = 0; ks < 4; ++ks)
                    acc3[ni][mt] = __builtin_amdgcn_mfma_f32_16x16x32_bf16(
                        a[ks], w3f[ni][ks], acc3[ni][mt], 0, 0, 0);
        }
#pragma unroll
        for (int ni = 0; ni < 2; ++ni) {
            float mx = -1e30f, mn = 1e30f, s = 0.f, q = 0.f;
#pragma unroll
            for (int mt = 0; mt < 3; ++mt)
#pragma unroll
                for (int r = 0; r < 4; ++r) {
                    int t = mt * 16 + lk * 4 + r;
                    if (t < TT) {
                        float h = acc3[ni][mt][r];
                        mx = fmaxf(mx, h); mn = fminf(mn, h);
                        s += h; q += h * h;
                    }
                }
            mx = fmaxf(mx, __shfl_xor(mx, 16)); mx = fmaxf(mx, __shfl_xor(mx, 32));
            mn = fminf(mn, __shfl_xor(mn, 16)); mn = fminf(mn, __shfl_xor(mn, 32));
            s += __shfl_xor(s, 16); s += __shfl_xor(s, 32);
            q += __shfl_xor(q, 16); q += __shfl_xor(q, 32);
            if (l < 16) {
                h3max[(size_t)n * 128 + c3[ni]] = mx;
                h3min[(size_t)n * 128 + c3[ni]] = mn;
                s3a[ni] += s; q3a[ni] += q;
            }
        }
    }
    if (l < 16) {
#pragma unroll
        for (int ni = 0; ni < 2; ++ni) {
            atomicAdd(&stats[S_BN3 + c3[ni]], s3a[ni]);
            atomicAdd(&stats[S_BN3 + 128 + c3[ni]], q3a[ni]);
        }
    }
}

// ------------------- owner resolution (last index wins) -------------------
__global__ void k_owner(const int* __restrict__ coords, int* __restrict__ owner)
{
    int n = blockIdx.x * 256 + threadIdx.x;
    if (n >= NVOX) return;
    int cx = coords[n * 4 + 1], cy = coords[n * 4 + 2], cz = coords[n * 4 + 3];
    atomicMax(&owner[(cx * GYD + cy) * GZD + cz], n);
}

// ---------- bn3+relu via max/min, scatter into dense [NPOS][128] bf16 ----------
__global__ __launch_bounds__(128) void k_scatter(
    const float* __restrict__ h3max, const float* __restrict__ h3min,
    const int* __restrict__ coords, const int* __restrict__ owner,
    const float* __restrict__ stats, __hip_bfloat16* __restrict__ dense)
{
    int n = blockIdx.x, k = threadIdx.x;
    int cx = coords[n * 4 + 1], cy = coords[n * 4 + 2], cz = coords[n * 4 + 3];
    int cell = (cx * GYD + cy) * GZD + cz;
    if (owner[cell] != n) return;
    float sc = stats[S_BN3 + 256 + k], sh = stats[S_BN3 + 384 + k];
    float h = (sc >= 0.f) ? h3max[(size_t)n * 128 + k] : h3min[(size_t)n * 128 + k];
    dense[(size_t)cell * 128 + k] = f2bf(fmaxf(h * sc + sh, 0.f));
}

// ---------- weight relayout: src [OC=64][IC][27] f32 -> dst [27][kk=IC/8][oc][8] bf16 ----------
__global__ void k_wcvt2(const float* __restrict__ src, __hip_bfloat16* __restrict__ dst,
                        int IC)
{
    int i = blockIdx.x * 256 + threadIdx.x;
    int total = 27 * 64 * IC;
    if (i >= total) return;
    int perd = 64 * IC;
    int d = i / perd, rem = i % perd;
    int kk = rem / 512;          // (k*4 + lk)
    int rem2 = rem % 512;
    int oc = rem2 >> 3, j = rem2 & 7;
    int ch = (kk >> 2) * 32 + (kk & 3) * 8 + j;
    dst[i] = f2bf(src[((size_t)oc * IC + ch) * 27 + d]);
}

// ---------- MFMA implicit-GEMM 3x3x3 conv, LDS-staged A + coalesced B ----------
template <int IC>
__global__ __launch_bounds__(256) void k_convm(
    const __hip_bfloat16* __restrict__ in, const __hip_bfloat16* __restrict__ wbn,
    const float* __restrict__ bias, __hip_bfloat16* __restrict__ outp,
    float* __restrict__ sumAcc, float* __restrict__ sqAcc)
{
    constexpr int KS = IC / 32;          // k-steps per tap
    constexpr int ROWB = IC * 2;         // bytes per row
    constexpr int CPR = ROWB / 16;       // 16B chunks per row
    __shared__ __align__(16) char atile[69 * ROWB];
    __shared__ float ssum[64], ssq[64];
    int tid = threadIdx.x;
    if (tid < 64) { ssum[tid] = 0.f; ssq[tid] = 0.f; }
    if (tid < CPR) *(int4v*)(atile + 68 * ROWB + tid * 16) = int4v{0, 0, 0, 0};

    int l = tid & 63, wave = tid >> 6;
    int wm = wave >> 1, wn = wave & 1;
    int lr = l & 15, lk = l >> 4;

    int pbase = blockIdx.x * 64;
    int p0 = pbase + wm * 32 + lr;       // mt=0 position
    int p1 = p0 + 16;                    // mt=1
    int z0 = p0 % 10, y0 = (p0 / 10) % 128, x0 = p0 / 1280;
    int z1 = p1 % 10, y1c = (p1 / 10) % 128, x1 = p1 / 1280;

    int oc0 = wn * 32 + lr, oc1 = oc0 + 16;
    const short8* wb8 = (const short8*)wbn;

    float bb0 = bias[oc0], bb1 = bias[oc1];
    f32x4 acc[2][2];
#pragma unroll
    for (int t = 0; t < 2; ++t) {
        acc[t][0] = { bb0, bb0, bb0, bb0 };
        acc[t][1] = { bb1, bb1, bb1, bb1 };
    }

    for (int g = 0; g < 9; ++g) {
        int dx = g / 3 - 1, dy = g % 3 - 1;
        int offg = (dx * 128 + dy) * 10;
        __syncthreads();                 // prior group's reads done
        for (int c = tid; c < 68 * CPR; c += 256) {
            int r = c / CPR, sub = c - r * CPR;
            int grow = pbase + offg - 1 + r;
            grow = grow < 0 ? 0 : (grow > NPOS - 1 ? NPOS - 1 : grow);
            int4v v = *(const int4v*)(in + (size_t)grow * IC + sub * 8);
            *(int4v*)(atile + r * ROWB + ((sub * 16) ^ ((r & 7) << 4))) = v;
        }
        __syncthreads();                 // stage ready
        bool vxy0 = ((unsigned)(x0 + dx) < 128u) & ((unsigned)(y0 + dy) < 128u);
        bool vxy1 = ((unsigned)(x1 + dx) < 128u) & ((unsigned)(y1c + dy) < 128u);
#pragma unroll
        for (int dzi = 0; dzi < 3; ++dzi) {
            int dz = dzi - 1;
            int d = g * 3 + dzi;
            bool v0 = vxy0 & ((unsigned)(z0 + dz) < 10u);
            bool v1 = vxy1 & ((unsigned)(z1 + dz) < 10u);
            int ra0 = v0 ? (wm * 32 + lr + dz + 1) : 68;
            int ra1 = v1 ? (wm * 32 + 16 + lr + dz + 1) : 68;
            short8 a0[KS], a1[KS], b0[KS], b1[KS];
#pragma unroll
            for (int k = 0; k < KS; ++k) {
                size_t bi = ((size_t)(d * KS + k) * 4 + lk) * 64;
                b0[k] = wb8[bi + oc0];
                b1[k] = wb8[bi + oc1];
                int xb = lk * 16 + k * 64;
                a0[k] = *(const short8*)(atile + ra0 * ROWB + (xb ^ ((ra0 & 7) << 4)));
                a1[k] = *(const short8*)(atile + ra1 * ROWB + (xb ^ ((ra1 & 7) << 4)));
            }
#pragma unroll
            for (int k = 0; k < KS; ++k) {
                acc[0][0] = __builtin_amdgcn_mfma_f32_16x16x32_bf16(a0[k], b0[k], acc[0][0], 0, 0, 0);
                acc[0][1] = __builtin_amdgcn_mfma_f32_16x16x32_bf16(a0[k], b1[k], acc[0][1], 0, 0, 0);
                acc[1][0] = __builtin_amdgcn_mfma_f32_16x16x32_bf16(a1[k], b0[k], acc[1][0], 0, 0, 0);
                acc[1][1] = __builtin_amdgcn_mfma_f32_16x16x32_bf16(a1[k], b1[k], acc[1][1], 0, 0, 0);
            }
        }
    }

    float s0 = 0.f, q0 = 0.f, s1 = 0.f, q1 = 0.f;
#pragma unroll
    for (int t = 0; t < 2; ++t) {
#pragma unroll
        for (int r = 0; r < 4; ++r) {
            int prow = pbase + wm * 32 + t * 16 + lk * 4 + r;
            float v0c = acc[t][0][r], v1c = acc[t][1][r];
            outp[(size_t)prow * 64 + oc0] = f2bf(v0c);
            outp[(size_t)prow * 64 + oc1] = f2bf(v1c);
            s0 += v0c; q0 += v0c * v0c;
            s1 += v1c; q1 += v1c * v1c;
        }
    }
    s0 += __shfl_xor(s0, 16); s0 += __shfl_xor(s0, 32);
    q0 += __shfl_xor(q0, 16); q0 += __shfl_xor(q0, 32);
    s1 += __shfl_xor(s1, 16); s1 += __shfl_xor(s1, 32);
    q1 += __shfl_xor(q1, 16); q1 += __shfl_xor(q1, 32);
    if (l < 16) {
        atomicAdd(&ssum[oc0], s0); atomicAdd(&ssq[oc0], q0);
        atomicAdd(&ssum[oc1], s1); atomicAdd(&ssq[oc1], q1);
    }
    __syncthreads();
    if (tid < 64) {
        atomicAdd(&sumAcc[tid], ssum[tid]);
        atomicAdd(&sqAcc[tid], ssq[tid]);
    }
}

// ---------- conv3: in [NPOS][64] -> y3 [NPOS][2] ----------
__global__ __launch_bounds__(256) void k_conv3(
    const __hip_bfloat16* __restrict__ in, const float* __restrict__ w,
    const float* __restrict__ bias, float* __restrict__ y3,
    float* __restrict__ sumAcc, float* __restrict__ sqAcc)
{
    __shared__ float wred[8];
    int tid = threadIdx.x;
    int p = blockIdx.x * 256 + tid;
    int z = p % 10, y = (p / 10) % 128, x = p / 1280;
    float a0 = bias[0], a1 = bias[1];
    for (int d = 0; d < 27; ++d) {
        int dx = d / 9 - 1, dy = (d / 3) % 3 - 1, dz = d % 3 - 1;
        if (!(((unsigned)(x + dx) < 128u) & ((unsigned)(y + dy) < 128u) & ((unsigned)(z + dz) < 10u)))
            continue;
        int off = (dx * 128 + dy) * 10 + dz;
        const short8* ip = (const short8*)(in + (size_t)(p + off) * 64);
#pragma unroll
        for (int cb = 0; cb < 8; ++cb) {
            short8 v = ip[cb];
#pragma unroll
            for (int j = 0; j < 8; ++j) {
                int ic = cb * 8 + j;
                float f = bfs2f(v[j]);
                a0 += f * w[(ic) * 27 + d];
                a1 += f * w[(64 + ic) * 27 + d];
            }
        }
    }
    y3[(size_t)p * 2 + 0] = a0;
    y3[(size_t)p * 2 + 1] = a1;

    float s0 = a0, q0 = a0 * a0, s1 = a1, q1 = a1 * a1;
    for (int o = 32; o > 0; o >>= 1) {
        s0 += __shfl_down(s0, o); q0 += __shfl_down(q0, o);
        s1 += __shfl_down(s1, o); q1 += __shfl_down(q1, o);
    }
    int wv = tid >> 6;
    if ((tid & 63) == 0) { wred[wv] = s0; wred[4 + wv] = q0; }
    __syncthreads();
    if ((tid & 63) == 0 && wv == 0) {
        atomicAdd(&sumAcc[0], wred[0] + wred[1] + wred[2] + wred[3]);
        atomicAdd(&sqAcc[0], wred[4] + wred[5] + wred[6] + wred[7]);
    }
    __syncthreads();
    if ((tid & 63) == 0) { wred[wv] = s1; wred[4 + wv] = q1; }
    __syncthreads();
    if ((tid & 63) == 0 && wv == 0) {
        atomicAdd(&sumAcc[1], wred[0] + wred[1] + wred[2] + wred[3]);
        atomicAdd(&sqAcc[1], wred[4] + wred[5] + wred[6] + wred[7]);
    }
}

// ---------- vectorized bn+relu in place, layout [NPOS][64] ----------
__global__ void k_bnrelu_v(__hip_bfloat16* __restrict__ ybuf,
                           const float* __restrict__ stats, int base)
{
    const int C = 64;
    int nvec = NPOS * C / 8;
    short8* yv = (short8*)ybuf;
    for (int i = blockIdx.x * 256 + threadIdx.x; i < nvec; i += gridDim.x * 256) {
        int cb = (i & 7) * 8;
        short8 v = yv[i];
        short8 r;
#pragma unroll
        for (int j = 0; j < 8; ++j) {
            float f = bfs2f(v[j]) * stats[base + 2 * C + cb + j] + stats[base + 3 * C + cb + j];
            r[j] = f2bfs(fmaxf(f, 0.f));
        }
        yv[i] = r;
    }
}

// ------------------- gather + bn + relu + softmax -------------------
__global__ void k_out(const float* __restrict__ y3, const int* __restrict__ coords,
                      const float* __restrict__ stats, float* __restrict__ out)
{
    int n = blockIdx.x * 256 + threadIdx.x;
    if (n >= NVOX) return;
    int cx = coords[n * 4 + 1], cy = coords[n * 4 + 2], cz = coords[n * 4 + 3];
    int cell = (cx * GYD + cy) * GZD + cz;
    float a = fmaxf(y3[(size_t)cell * 2 + 0] * stats[S_C3 + 4] + stats[S_C3 + 6], 0.f);
    float b = fmaxf(y3[(size_t)cell * 2 + 1] * stats[S_C3 + 5] + stats[S_C3 + 7], 0.f);
    float m = fmaxf(a, b);
    float e0 = expf(a - m), e1 = expf(b - m);
    float inv = 1.f / (e0 + e1);
    out[n * 2 + 0] = e0 * inv;
    out[n * 2 + 1] = e1 * inv;
}

extern "C" void kernel_launch(void* const* d_in, const int* in_sizes, int n_in,
                              void* d_out, int out_size, void* d_ws, size_t ws_size,
                              hipStream_t stream)
{
    const float* vf     = (const float*)d_in[0];
    const int*   coords = (const int*)d_in[1];
    const float* w1  = (const float*)d_in[2];
    const float* b1  = (const float*)d_in[3];
    const float* g1  = (const float*)d_in[4];
    const float* be1 = (const float*)d_in[5];
    const float* w2  = (const float*)d_in[6];
    const float* b2  = (const float*)d_in[7];
    const float* g2  = (const float*)d_in[8];
    const float* be2 = (const float*)d_in[9];
    const float* w3  = (const float*)d_in[10];
    const float* b3  = (const float*)d_in[11];
    const float* g3  = (const float*)d_in[12];
    const float* be3 = (const float*)d_in[13];
    const float* c1w = (const float*)d_in[14];
    const float* c1b = (const float*)d_in[15];
    const float* c1g = (const float*)d_in[16];
    const float* c1be= (const float*)d_in[17];
    const float* c2w = (const float*)d_in[18];
    const float* c2b = (const float*)d_in[19];
    const float* c2g = (const float*)d_in[20];
    const float* c2be= (const float*)d_in[21];
    const float* c3w = (const float*)d_in[22];
    const float* c3b = (const float*)d_in[23];
    const float* c3g = (const float*)d_in[24];
    const float* c3be= (const float*)d_in[25];

    if (ws_size < WS_BYTES) return;

    char* base = (char*)d_ws;
    float* stats = (float*)(base + O_STATS);
    __hip_bfloat16* zp = (__hip_bfloat16*)(base + O_ZERO);
    int*   owner = (int*)(base + O_OWNER);
    float* Gg    = (float*)(base + O_G);
    float* G7    = Gg + 1088;
    float* h3max = (float*)(base + O_H3MAX);
    float* h3min = (float*)(base + O_H3MIN);
    __hip_bfloat16* wb1 = (__hip_bfloat16*)(base + O_WB1);
    __hip_bfloat16* wb2 = (__hip_bfloat16*)(base + O_WB2);
    __hip_bfloat16* pcg = (__hip_bfloat16*)(base + O_PC);
    float* mkg          = (float*)(base + O_MKF);
    __hip_bfloat16* dense = (__hip_bfloat16*)(base + O_DENSE);
    __hip_bfloat16* y1    = (__hip_bfloat16*)(base + O_Y1);
    __hip_bfloat16* y2    = (__hip_bfloat16*)(base + O_Y2);
    float* y3             = (float*)(base + O_Y3);

    hipMemsetAsync(stats, 0, STATS_FLOATS * sizeof(float), stream);
    hipMemsetAsync((void*)zp, 0, 256, stream);
    hipMemsetAsync(owner, 0xFF, (size_t)NPOS * sizeof(int), stream);
    hipMemsetAsync(Gg, 0, 1152 * sizeof(float), stream);

    k_gram7<<<1024, 256, 0, stream>>>(vf, G7);
    k_bn1g<<<1, 64, 0, stream>>>(G7, w1, b1, g1, be1, stats);
    k_pc<<<NVOX / VB, 256, 0, stream>>>(vf, stats, pcg, mkg, Gg, w1, b1);
    k_bn2g<<<1, 64, 0, stream>>>(Gg, w2, b2, g2, be2, stats);
    k_vfe3m<<<1024, 256, 0, stream>>>(pcg, mkg, stats, h3max, h3min,
                                      w2, b2, w3, b3, zp);
    k_finalize<<<1, 128, 0, stream>>>(stats, S_BN3, 128, 1.f / NTR, g3, be3);
    k_owner<<<(NVOX + 255) / 256, 256, 0, stream>>>(coords, owner);
    hipMemsetAsync((void*)dense, 0, (size_t)NPOS * 128 * sizeof(__hip_bfloat16), stream);
    k_scatter<<<NVOX, 128, 0, stream>>>(h3max, h3min, coords, owner, stats, dense);

    k_wcvt2<<<(64 * 128 * 27 + 255) / 256, 256, 0, stream>>>(c1w, wb1, 128);
    k_wcvt2<<<(64 * 64 * 27 + 255) / 256, 256, 0, stream>>>(c2w, wb2, 64);

    k_convm<128><<<NPOS / 64, 256, 0, stream>>>(dense, wb1, c1b, y1,
                                                &stats[S_C1], &stats[S_C1 + 64]);
    k_finalize<<<1, 128, 0, stream>>>(stats, S_C1, 64, 1.f / NPOS, c1g, c1be);
    k_bnrelu_v<<<1024, 256, 0, stream>>>(y1, stats, S_C1);

    k_convm<64><<<NPOS / 64, 256, 0, stream>>>(y1, wb2, c2b, y2,
                                               &stats[S_C2], &stats[S_C2 + 64]);
    k_finalize<<<1, 128, 0, stream>>>(stats, S_C2, 64, 1.f / NPOS, c2g, c2be);
    k_bnrelu_v<<<1024, 256, 0, stream>>>(y2, stats, S_C2);

    k_conv3<<<NPOS / 256, 256, 0, stream>>>(y2, c3w, c3b, y3,
                                            &stats[S_C3], &stats[S_C3 + 2]);
    k_finalize<<<1, 128, 0, stream>>>(stats, S_C3, 2, 1.f / NPOS, c3g, c3be);

    k_out<<<(NVOX + 255) / 256, 256, 0, stream>>>(y3, coords, stats, (float*)d_out);
}